// Round 11
// baseline (196.607 us; speedup 1.0000x reference)
//
#include <hip/hip_runtime.h>

// ---------------------------------------------------------------------------
// SelfAttention fused pipeline for MI355X (gfx950)
// B=4 S=1024 DIM=2048 H=16 KV=4 HD=128 ROPE_DIM=64
//
// Stages (all on `stream`), 5 launches:
//  1) prep: casts fp32->bf16 (x | Wq|Wk|Wv | Wproj) + rope cos/sin table
//  2) gemm8p_qkv: qkv = xb @ Wcat^T -- 256^2 tile, BK=64, 8-phase schedule
//     (4 phases/K-tile, counted vmcnt(6), raw s_barrier, setprio, swizzled
//      LDS) + fused RMSNorm/RoPE/log2-prescale epilogue
//  3) vtrans: V -> Vt_global[b,kvh][d][kv] (pre-swizzled for LDS staging)
//  4) attn_fwd: causal flash attention + v-proj correction -> y bf16
//  5) gemm_bt: out = y @ Wproj^T (128^2 dbuf stage-early, fp32 out)
// ---------------------------------------------------------------------------

typedef __attribute__((ext_vector_type(8))) __bf16 bf16x8;
typedef __attribute__((ext_vector_type(4))) __bf16 bf16x4;
typedef __attribute__((ext_vector_type(4))) float f32x4;

static_assert(sizeof(__bf16) == 2, "bf16 size");

#define MFMA16x16x32(a, b, c) __builtin_amdgcn_mfma_f32_16x16x32_bf16((a), (b), (c), 0, 0, 0)

#if __has_builtin(__builtin_amdgcn_exp2f)
#define EXP2(x) __builtin_amdgcn_exp2f(x)
#else
#define EXP2(x) exp2f(x)
#endif

__device__ __forceinline__ void gload_lds16(const void* g, void* l) {
  __builtin_amdgcn_global_load_lds((const __attribute__((address_space(1))) void*)g,
                                   (__attribute__((address_space(3))) void*)l, 16, 0, 0);
}

// ---------------- 1) prep: all casts + rope table, one kernel ----------------
__global__ __launch_bounds__(256) void prep(const float* __restrict__ x,
                                            const float* __restrict__ wq,
                                            const float* __restrict__ wk,
                                            const float* __restrict__ wv,
                                            const float* __restrict__ wp,
                                            __bf16* __restrict__ xb,
                                            __bf16* __restrict__ wb,
                                            __bf16* __restrict__ wpb,
                                            float2* __restrict__ tab) {
  constexpr int NX = 2097152;   // 4096*2048/4
  constexpr int NW1 = 1048576;  // 2048*2048/4
  constexpr int NW2 = 262144;   // 512*2048/4
  constexpr int NP = 1048576;   // 2048*2048/4
  constexpr int NT = 32768;     // 1024*32 rope table entries
  constexpr int TOT = NX + NW1 + 2 * NW2 + NP + NT;
  auto cast4 = [](const float* s, __bf16* d, int i) {
    f32x4 v = ((const f32x4*)s)[i];
    bf16x4 o;
    o[0] = (__bf16)v[0];
    o[1] = (__bf16)v[1];
    o[2] = (__bf16)v[2];
    o[3] = (__bf16)v[3];
    ((bf16x4*)d)[i] = o;
  };
  int i = blockIdx.x * blockDim.x + threadIdx.x;
  const int stride = gridDim.x * blockDim.x;
  for (; i < TOT; i += stride) {
    int j = i;
    if (j < NX) {
      cast4(x, xb, j);
    } else if ((j -= NX) < NW1) {
      cast4(wq, wb, j);
    } else if ((j -= NW1) < NW2) {
      cast4(wk, wb + (size_t)NW1 * 4, j);
    } else if ((j -= NW2) < NW2) {
      cast4(wv, wb + (size_t)(NW1 + NW2) * 4, j);
    } else if ((j -= NW2) < NP) {
      cast4(wp, wpb, j);
    } else {
      j -= NP;  // rope table: entry (s, jj)
      const int s = j >> 5, jj = j & 31;
      const float inv = powf(10000.0f, -(float)jj * 0.03125f);
      const float ang = (float)s * inv;
      tab[j] = make_float2(cosf(ang), sinf(ang));
    }
  }
}

// ---------------- 2) QKV GEMM: 256^2 8-phase template + fused norm/rope ------
// C[M,N] = A[M,K]*B[N,K]^T, M=4096 N=3072 K=2048. 512 thr, 8 waves (2Mx4N),
// per-wave 128x64 (acc[8][4]). BK=64, 2 LDS buffers (128 KB). Half-tiles
// (A0=rows0-127, A1, B0, B1; 2 gload_lds/thread each). Stage stream runs 3
// half-tiles ahead: per tile-group {ph1: B1(t+1); ph4: A0,A1,B0(t+2)};
// vmcnt(6) at ph4 only (never 0 mid-loop). Raw s_barrier (no vmcnt drain);
// lgkmcnt(0)+sched_barrier(0) pins reads in-phase (WAR-safe vs ph4 stages).
// LDS [.][64] col-group swizzle cg^(row&7) (R9-verified conflict-free) via
// inverse-swizzled global source. Epilogue: 256-col tile = 2 heads ->
// RMSNorm (lane butterfly + LDS cross-wave) + partial RoPE + q log2-prescale.
__global__ __launch_bounds__(512) void gemm8p_qkv(const __bf16* __restrict__ A,
                                                  const __bf16* __restrict__ B,
                                                  __bf16* __restrict__ C, int N, int K,
                                                  int nbn, const float2* __restrict__ tab) {
  __shared__ __bf16 As[2][256 * 64];
  __shared__ __bf16 Bs[2][256 * 64];

  const int nwg = gridDim.x;
  const int id = blockIdx.x;
  const int xid = (id & 7) * (nwg >> 3) + (id >> 3);
  const int bm = xid / nbn;
  const int bn = xid - bm * nbn;

  const int t = threadIdx.x;
  const int l = t & 63, w = t >> 6;
  const int wr = w >> 2, wc = w & 3;  // 2M x 4N wave grid
  const int lr = l & 15, lk = l >> 4;
  const int swz = lr & 7;
  const __bf16* Ab = A + (size_t)bm * 256 * K;
  const __bf16* Bb = B + (size_t)bn * 256 * K;
  const int NT = K >> 6;  // 32

  // stage one half-tile (h: 0=A rows0-127, 1=A rows128-255, 2=B0, 3=B1)
  auto stageHalf = [&](int kt, int h) {
    const int buf = kt & 1;
    const __bf16* src = (h < 2) ? Ab : Bb;
    __bf16* dst = ((h < 2) ? &As[buf][0] : &Bs[buf][0]) + (h & 1) * 8192;
    const int k0 = kt << 6;
    const int rb0 = (h & 1) * 128;
#pragma unroll
    for (int r = 0; r < 2; ++r) {
      const int row = rb0 + r * 64 + (t >> 3);
      const int cs = ((t & 7) ^ (row & 7)) << 3;  // inverse swizzle on source
      gload_lds16(src + (size_t)row * K + k0 + cs, dst + r * 4096 + t * 8);
    }
  };

  f32x4 acc[8][4] = {};
  bf16x8 aR[4][2], bR[4][2];

  // prologue: tile0 complete + 3 halves of tile1 in flight
  stageHalf(0, 0);
  stageHalf(0, 1);
  stageHalf(0, 2);
  stageHalf(0, 3);
  stageHalf(1, 0);
  stageHalf(1, 1);
  stageHalf(1, 2);
  asm volatile("s_waitcnt vmcnt(6)" ::: "memory");
  __builtin_amdgcn_sched_barrier(0);
  __builtin_amdgcn_s_barrier();

  for (int kt = 0; kt < NT; ++kt) {
    const int buf = kt & 1;

    // ---- phase 1: read A m0-3 + B n0-1 | stage B1(t+1) | MFMA q(0,0) ----
#pragma unroll
    for (int m = 0; m < 4; ++m)
#pragma unroll
      for (int kk = 0; kk < 2; ++kk) {
        const int row = wr * 128 + m * 16 + lr;
        aR[m][kk] = *(const bf16x8*)&As[buf][row * 64 + (((kk * 4 + lk) ^ swz) << 3)];
      }
#pragma unroll
    for (int n = 0; n < 2; ++n)
#pragma unroll
      for (int kk = 0; kk < 2; ++kk) {
        const int row = wc * 64 + n * 16 + lr;
        bR[n][kk] = *(const bf16x8*)&Bs[buf][row * 64 + (((kk * 4 + lk) ^ swz) << 3)];
      }
    if (kt + 1 < NT) stageHalf(kt + 1, 3);
    __builtin_amdgcn_s_barrier();
    asm volatile("s_waitcnt lgkmcnt(0)" ::: "memory");
    __builtin_amdgcn_sched_barrier(0);
    __builtin_amdgcn_s_setprio(1);
#pragma unroll
    for (int m = 0; m < 4; ++m)
#pragma unroll
      for (int n = 0; n < 2; ++n)
#pragma unroll
        for (int kk = 0; kk < 2; ++kk)
          acc[m][n] = MFMA16x16x32(aR[m][kk], bR[n][kk], acc[m][n]);
    __builtin_amdgcn_s_setprio(0);
    __builtin_amdgcn_s_barrier();

    // ---- phase 2: read B n2-3 | MFMA q(0,1) ----
#pragma unroll
    for (int n = 0; n < 2; ++n)
#pragma unroll
      for (int kk = 0; kk < 2; ++kk) {
        const int row = wc * 64 + (n + 2) * 16 + lr;
        bR[n + 2][kk] = *(const bf16x8*)&Bs[buf][row * 64 + (((kk * 4 + lk) ^ swz) << 3)];
      }
    __builtin_amdgcn_s_barrier();
    asm volatile("s_waitcnt lgkmcnt(0)" ::: "memory");
    __builtin_amdgcn_sched_barrier(0);
    __builtin_amdgcn_s_setprio(1);
#pragma unroll
    for (int m = 0; m < 4; ++m)
#pragma unroll
      for (int n = 0; n < 2; ++n)
#pragma unroll
        for (int kk = 0; kk < 2; ++kk)
          acc[m][n + 2] = MFMA16x16x32(aR[m][kk], bR[n + 2][kk], acc[m][n + 2]);
    __builtin_amdgcn_s_setprio(0);
    __builtin_amdgcn_s_barrier();

    // ---- phase 3: read A m4-7 | MFMA q(1,0) ----
#pragma unroll
    for (int m = 0; m < 4; ++m)
#pragma unroll
      for (int kk = 0; kk < 2; ++kk) {
        const int row = wr * 128 + (m + 4) * 16 + lr;
        aR[m][kk] = *(const bf16x8*)&As[buf][row * 64 + (((kk * 4 + lk) ^ swz) << 3)];
      }
    __builtin_amdgcn_s_barrier();
    asm volatile("s_waitcnt lgkmcnt(0)" ::: "memory");
    __builtin_amdgcn_sched_barrier(0);
    __builtin_amdgcn_s_setprio(1);
#pragma unroll
    for (int m = 0; m < 4; ++m)
#pragma unroll
      for (int n = 0; n < 2; ++n)
#pragma unroll
        for (int kk = 0; kk < 2; ++kk)
          acc[m + 4][n] = MFMA16x16x32(aR[m][kk], bR[n][kk], acc[m + 4][n]);
    __builtin_amdgcn_s_setprio(0);
    __builtin_amdgcn_s_barrier();

    // ---- phase 4: stage A0,A1,B0(t+2) | vmcnt(6) | MFMA q(1,1) ----
    if (kt + 2 < NT) {
      stageHalf(kt + 2, 0);
      stageHalf(kt + 2, 1);
      stageHalf(kt + 2, 2);
    }
    if (kt < NT - 2)
      asm volatile("s_waitcnt vmcnt(6)" ::: "memory");  // tile t+1 landed
    else
      asm volatile("s_waitcnt vmcnt(0)" ::: "memory");  // tail drain
    __builtin_amdgcn_sched_barrier(0);
    __builtin_amdgcn_s_barrier();
    __builtin_amdgcn_s_setprio(1);
#pragma unroll
    for (int m = 0; m < 4; ++m)
#pragma unroll
      for (int n = 0; n < 2; ++n)
#pragma unroll
        for (int kk = 0; kk < 2; ++kk)
          acc[m + 4][n + 2] = MFMA16x16x32(aR[m][kk], bR[n + 2][kk], acc[m + 4][n + 2]);
    __builtin_amdgcn_s_setprio(0);
    __builtin_amdgcn_s_barrier();
  }

  __syncthreads();  // full drain before LDS reuse

  // epilogue: bn 0-7 = q (rope+norm+log2 prescale), 8-9 = k (rope+norm),
  // 10-11 = v (plain store). Tile = 2 heads: hh = wc>>1.
  if (bn < 10) {
    float* Ls = (float*)&As[0][0];  // [4][256] row sum-of-squares per wc
#pragma unroll
    for (int m = 0; m < 8; ++m) {
#pragma unroll
      for (int i = 0; i < 4; ++i) {
        float s = 0.0f;
#pragma unroll
        for (int n = 0; n < 4; ++n) s += acc[m][n][i] * acc[m][n][i];
#pragma unroll
        for (int off = 1; off < 16; off <<= 1) s += __shfl_xor(s, off);
        if (lr == 0) Ls[wc * 256 + wr * 128 + m * 16 + lk * 4 + i] = s;
      }
    }
    __syncthreads();
    const bool isq = (bn < 8);
    const float qs = isq ? 0.1275174457f : 1.0f;  // (1/sqrt(128))*log2(e)
    const int hh = wc >> 1;
#pragma unroll
    for (int m = 0; m < 8; ++m) {
#pragma unroll
      for (int i = 0; i < 4; ++i) {
        const int rl = wr * 128 + m * 16 + lk * 4 + i;
        const int rg = bm * 256 + rl;
        const float sc = rsqrtf((Ls[2 * hh * 256 + rl] + Ls[(2 * hh + 1) * 256 + rl]) *
                                    (1.0f / 128.0f) +
                                1.1920928955078125e-07f) *
                         qs;
        __bf16* Cr = C + (size_t)rg * N + bn * 256 + hh * 128;
        if ((wc & 1) == 0) {  // rotated half (cols 0-63 of head)
          const int s = rg & 1023;
#pragma unroll
          for (int n = 0; n < 2; ++n) {
            const int j = n * 16 + lr;
            const float2 cs2 = tab[s * 32 + j];
            const float x1 = acc[m][n][i], x2 = acc[m][n + 2][i];
            Cr[j] = (__bf16)((x1 * cs2.x + x2 * cs2.y) * sc);
            Cr[j + 32] = (__bf16)((-x1 * cs2.y + x2 * cs2.x) * sc);
          }
        } else {  // plain half (cols 64-127 of head)
#pragma unroll
          for (int n = 0; n < 4; ++n)
            Cr[64 + n * 16 + lr] = (__bf16)(acc[m][n][i] * sc);
        }
      }
    }
  } else {
#pragma unroll
    for (int m = 0; m < 8; ++m) {
      const int row0 = bm * 256 + wr * 128 + m * 16 + lk * 4;
#pragma unroll
      for (int n = 0; n < 4; ++n) {
        const int col = bn * 256 + wc * 64 + n * 16 + lr;
#pragma unroll
        for (int i = 0; i < 4; ++i)
          C[(size_t)(row0 + i) * N + col] = (__bf16)acc[m][n][i];
      }
    }
  }
}

// ---------------- 5) proj GEMM: 128^2 dbuf stage-early + swizzle (R8) --------
template <typename CT>
__global__ __launch_bounds__(256) void gemm_bt(const __bf16* __restrict__ A,
                                               const __bf16* __restrict__ B,
                                               CT* __restrict__ C, int N, int K, int nbn) {
  __shared__ __bf16 As[2][128 * 32];
  __shared__ __bf16 Bs[2][128 * 32];
  const int nwg = gridDim.x;
  const int id = blockIdx.x;
  const int xid = (id & 7) * (nwg >> 3) + (id >> 3);
  const int bm = xid / nbn;
  const int bn = xid - bm * nbn;
  const int t = threadIdx.x;
  const int l = t & 63, w = t >> 6;
  const int wr = w >> 1, wc = w & 1;
  const int lr = l & 15, lk = l >> 4;
  const __bf16* Ab = A + (size_t)bm * 128 * K;
  const __bf16* Bb = B + (size_t)bn * 128 * K;
  const int srow = t >> 2;
  const int scol = ((t & 3) ^ ((srow >> 1) & 3)) << 3;
  f32x4 acc[4][4] = {};

  auto stage = [&](int k0, int buf) {
    gload_lds16(Ab + (size_t)srow * K + k0 + scol, &As[buf][t * 8]);
    gload_lds16(Ab + (size_t)(srow + 64) * K + k0 + scol, &As[buf][2048 + t * 8]);
    gload_lds16(Bb + (size_t)srow * K + k0 + scol, &Bs[buf][t * 8]);
    gload_lds16(Bb + (size_t)(srow + 64) * K + k0 + scol, &Bs[buf][2048 + t * 8]);
  };

  stage(0, 0);
  __syncthreads();

  const int NT = K >> 5;
  for (int kt = 0; kt < NT; ++kt) {
    const int cur = kt & 1;
    if (kt + 1 < NT) stage((kt + 1) << 5, cur ^ 1);

    bf16x8 af[4], bfr[4];
#pragma unroll
    for (int m = 0; m < 4; ++m) {
      const int row = wr * 64 + m * 16 + lr;
      af[m] = *(const bf16x8*)&As[cur][row * 32 + ((lk ^ ((row >> 1) & 3)) << 3)];
    }
#pragma unroll
    for (int n = 0; n < 4; ++n) {
      const int row = wc * 64 + n * 16 + lr;
      bfr[n] = *(const bf16x8*)&Bs[cur][row * 32 + ((lk ^ ((row >> 1) & 3)) << 3)];
    }
#pragma unroll
    for (int m = 0; m < 4; ++m)
#pragma unroll
      for (int n = 0; n < 4; ++n) acc[m][n] = MFMA16x16x32(af[m], bfr[n], acc[m][n]);

    __syncthreads();
  }

#pragma unroll
  for (int m = 0; m < 4; ++m) {
    const int row0 = bm * 128 + wr * 64 + m * 16 + lk * 4;
#pragma unroll
    for (int n = 0; n < 4; ++n) {
      const int col = bn * 128 + wc * 64 + n * 16 + lr;
#pragma unroll
      for (int i = 0; i < 4; ++i) C[(size_t)(row0 + i) * N + col] = (CT)acc[m][n][i];
    }
  }
}

// ---------------- 3) V transpose: Vt[b,kvh][d][kv ^ ((d&7)<<3)] -------------
__global__ __launch_bounds__(256) void vtrans(const __bf16* __restrict__ qkv,
                                              __bf16* __restrict__ vt) {
  __shared__ __bf16 L[64 * 128];
  const int tile = blockIdx.x;  // (b*4+kvh)*16 + st
  const int st = tile & 15, bk = tile >> 4;
  const int b = bk >> 2, kvh = bk & 3;
  const int t = threadIdx.x;
  const int s0 = st * 64;
  const __bf16* src = qkv + ((size_t)(b * 1024 + s0)) * 3072 + 2560 + kvh * 128;
#pragma unroll
  for (int r = 0; r < 4; ++r) {
    const int off = r * 2048 + t * 8;
    const int s = off >> 7, d = off & 127;
    bf16x8 v = *(const bf16x8*)(src + (size_t)s * 3072 + d);
    *(bf16x8*)&L[s * 128 + (d ^ ((s & 7) << 3) ^ (((s >> 3) & 7) << 3))] = v;
  }
  __syncthreads();
  __bf16* dst = vt + (size_t)bk * 128 * 1024;
#pragma unroll
  for (int r = 0; r < 4; ++r) {
    const int off = r * 2048 + t * 8;
    const int d = off >> 6, sc = off & 63;
    bf16x8 v;
#pragma unroll
    for (int j = 0; j < 8; ++j) {
      const int s = sc + j;
      v[j] = L[s * 128 + (d ^ ((s & 7) << 3) ^ (((s >> 3) & 7) << 3))];
    }
    *(bf16x8*)&dst[(size_t)d * 1024 + ((s0 + sc) ^ ((d & 7) << 3))] = v;
  }
}

// ---------------- 4) causal flash attention + v-projection correction ------
__global__ __launch_bounds__(512) void attn_fwd(const __bf16* __restrict__ qkv,
                                                const __bf16* __restrict__ vt,
                                                __bf16* __restrict__ y) {
  const int id = blockIdx.x;
  const int g = (id & 7) | (((id >> 3) & 1) << 3);  // (b,kvh) group 0..15
  const int b = g >> 2, kvh = g & 3;
  const int hi = (id >> 4) & 3;
  const int pr = (id >> 6) & 3;
  const int h = kvh * 4 + hi;

  const int t = threadIdx.x;
  const int l = t & 63, w = t >> 6;  // 8 waves
  const int lr = l & 15, lk = l >> 4;
  const int lr8 = lr & 7;

  __shared__ __bf16 Ks[2][64 * 128];
  __shared__ __bf16 Vs[2][128 * 64];
  __shared__ __bf16 Ps[8][16 * 64];

  const size_t rb = (size_t)b * 1024;
  const __bf16* Kg0 = qkv + rb * 3072 + 2048 + kvh * 128;
  const __bf16* Vtb = vt + (size_t)(b * 4 + kvh) * 128 * 1024;

  const int koff0 = t * 8;
  const int krow0 = koff0 >> 7;
  const int kcol0 = (koff0 & 127) ^ ((krow0 & 7) << 3);
  const int koff1 = 4096 + t * 8;
  const int krow1 = koff1 >> 7;
  const int kcol1 = (koff1 & 127) ^ ((krow1 & 7) << 3);
  const int voff0 = t * 8, voff1 = 4096 + t * 8;

#pragma unroll 1
  for (int pass = 0; pass < 2; ++pass) {
    const int qt = pass ? (7 - pr) : pr;
    const int q0 = qt << 7;

    bf16x8 aq[4];
    {
      const __bf16* qrow = qkv + (rb + q0 + w * 16 + lr) * 3072 + h * 128 + lk * 8;
#pragma unroll
      for (int kk = 0; kk < 4; ++kk) aq[kk] = *(const bf16x8*)(qrow + kk * 32);
    }

    float m_i[4], l_i[4];
    f32x4 o[8] = {};
#pragma unroll
    for (int i = 0; i < 4; ++i) {
      m_i[i] = -1e30f;
      l_i[i] = 0.0f;
    }

    const int rowg0 = q0 + w * 16 + lk * 4;
    const int wmin = q0 + w * 16;
    const int wmax = wmin + 15;
    const int nt = 2 * qt + 2;

    gload_lds16(Kg0 + (size_t)krow0 * 3072 + kcol0, &Ks[0][0] + koff0);
    gload_lds16(Kg0 + (size_t)krow1 * 3072 + kcol1, &Ks[0][0] + koff1);
    gload_lds16(Vtb + (size_t)(voff0 >> 6) * 1024 + (voff0 & 63), &Vs[0][0] + voff0);
    gload_lds16(Vtb + (size_t)(voff1 >> 6) * 1024 + (voff1 & 63), &Vs[0][0] + voff1);
    __syncthreads();

    for (int tt = 0; tt < nt; ++tt) {
      const int kv0 = tt * 64;
      const int cur = tt & 1;
      if (tt + 1 < nt) {
        const int nkv = kv0 + 64;
        const __bf16* Kg = Kg0 + (size_t)nkv * 3072;
        __bf16* kd = &Ks[cur ^ 1][0];
        __bf16* vd = &Vs[cur ^ 1][0];
        gload_lds16(Kg + (size_t)krow0 * 3072 + kcol0, kd + koff0);
        gload_lds16(Kg + (size_t)krow1 * 3072 + kcol1, kd + koff1);
        gload_lds16(Vtb + (size_t)(voff0 >> 6) * 1024 + nkv + (voff0 & 63), vd + voff0);
        gload_lds16(Vtb + (size_t)(voff1 >> 6) * 1024 + nkv + (voff1 & 63), vd + voff1);
      }

      if (kv0 <= wmax) {
        f32x4 sacc[4] = {};
        __builtin_amdgcn_s_setprio(1);
#pragma unroll
        for (int kk = 0; kk < 4; ++kk) {
#pragma unroll
          for (int n = 0; n < 4; ++n) {
            const bf16x8 bk = *(const bf16x8*)&Ks[cur][(n * 16 + lr) * 128 +
                                                      ((kk * 32 + lk * 8) ^ (lr8 << 3))];
            sacc[n] = MFMA16x16x32(aq[kk], bk, sacc[n]);
          }
        }
        __builtin_amdgcn_s_setprio(0);

        float pm[4];
#pragma unroll
        for (int i = 0; i < 4; ++i) pm[i] = -1e30f;
        if (kv0 + 63 > wmin) {
#pragma unroll
          for (int n = 0; n < 4; ++n) {
            const int colg = kv0 + n * 16 + lr;
#pragma unroll
            for (int i = 0; i < 4; ++i) {
              if (colg > rowg0 + i) sacc[n][i] = -1e30f;
              pm[i] = fmaxf(pm[i], sacc[n][i]);
            }
          }
        } else {
#pragma unroll
          for (int n = 0; n < 4; ++n)
#pragma unroll
            for (int i = 0; i < 4; ++i) pm[i] = fmaxf(pm[i], sacc[n][i]);
        }
#pragma unroll
        for (int i = 0; i < 4; ++i) {
          pm[i] = fmaxf(pm[i], __shfl_xor(pm[i], 1));
          pm[i] = fmaxf(pm[i], __shfl_xor(pm[i], 2));
          pm[i] = fmaxf(pm[i], __shfl_xor(pm[i], 4));
          pm[i] = fmaxf(pm[i], __shfl_xor(pm[i], 8));
        }
        float alpha[4], rs[4];
#pragma unroll
        for (int i = 0; i < 4; ++i) {
          const float mn = fmaxf(m_i[i], pm[i]);
          alpha[i] = EXP2(m_i[i] - mn);
          m_i[i] = mn;
          rs[i] = 0.0f;
        }
#pragma unroll
        for (int n = 0; n < 4; ++n) {
#pragma unroll
          for (int i = 0; i < 4; ++i) {
            const float p = EXP2(sacc[n][i] - m_i[i]);
            rs[i] += p;
            const int prow = lk * 4 + i;
            Ps[w][prow * 64 + ((n * 16 + lr) ^ ((prow & 7) << 3))] = (__bf16)p;
          }
        }
#pragma unroll
        for (int i = 0; i < 4; ++i) {
          rs[i] += __shfl_xor(rs[i], 1);
          rs[i] += __shfl_xor(rs[i], 2);
          rs[i] += __shfl_xor(rs[i], 4);
          rs[i] += __shfl_xor(rs[i], 8);
          l_i[i] = l_i[i] * alpha[i] + rs[i];
        }
#pragma unroll
        for (int f = 0; f < 8; ++f)
#pragma unroll
          for (int i = 0; i < 4; ++i) o[f][i] *= alpha[i];

        __builtin_amdgcn_s_setprio(1);
#pragma unroll
        for (int ks = 0; ks < 2; ++ks) {
          const bf16x8 pa =
              *(const bf16x8*)&Ps[w][lr * 64 + ((ks * 32 + lk * 8) ^ (lr8 << 3))];
#pragma unroll
          for (int f = 0; f < 8; ++f) {
            const bf16x8 vb = *(const bf16x8*)&Vs[cur][(f * 16 + lr) * 64 +
                                                       ((ks * 32 + lk * 8) ^ (lr8 << 3))];
            o[f] = MFMA16x16x32(pa, vb, o[f]);
          }
        }
        __builtin_amdgcn_s_setprio(0);
      }

      __syncthreads();
    }

#pragma unroll
    for (int i = 0; i < 4; ++i) {
      const int sg = rowg0 + i;
      const size_t mg = rb + sg;
      const __bf16* vp = qkv + mg * 3072 + 2560 + kvh * 128;
      const float invl = 1.0f / l_i[i];
      float vvv[8], yvv[8];
      float dyv = 0.0f, dvv = 0.0f;
#pragma unroll
      for (int f = 0; f < 8; ++f) {
        const float vf = (float)vp[f * 16 + lr];
        const float yf = o[f][i] * invl;
        vvv[f] = vf;
        yvv[f] = yf;
        dyv += yf * vf;
        dvv += vf * vf;
      }
#pragma unroll
      for (int off = 1; off < 16; off <<= 1) {
        dyv += __shfl_xor(dyv, off);
        dvv += __shfl_xor(dvv, off);
      }
      const float proj = dyv / fmaxf(dvv, 1e-6f);
      __bf16* yp = y + mg * 2048 + h * 128;
#pragma unroll
      for (int f = 0; f < 8; ++f) yp[f * 16 + lr] = (__bf16)(yvv[f] - proj * vvv[f]);
    }
  }
}

// ---------------------------------------------------------------------------
extern "C" void kernel_launch(void* const* d_in, const int* in_sizes, int n_in,
                              void* d_out, int out_size, void* d_ws, size_t ws_size,
                              hipStream_t stream) {
  const float* x = (const float*)d_in[0];
  const float* Wq = (const float*)d_in[2];
  const float* Wk = (const float*)d_in[3];
  const float* Wv = (const float*)d_in[4];
  const float* Wp = (const float*)d_in[5];
  float* out = (float*)d_out;

  __bf16* xb = (__bf16*)d_ws;                // 4096x2048
  __bf16* Wb = xb + (size_t)4096 * 2048;     // 3072x2048  [Wq;Wk;Wv]
  __bf16* Wpb = Wb + (size_t)3072 * 2048;    // 2048x2048
  __bf16* qkv = Wpb + (size_t)2048 * 2048;   // 4096x3072
  __bf16* yb = qkv + (size_t)4096 * 3072;    // 4096x2048
  float2* tab = (float2*)(yb + (size_t)4096 * 2048);  // 1024x32 cos/sin
  __bf16* vt = xb;  // reuse xb region after qkv GEMM (4*4*128*1024 elems)

  prep<<<2048, 256, 0, stream>>>(x, Wq, Wk, Wv, Wp, xb, Wb, Wpb, tab);

  gemm8p_qkv<<<192, 512, 0, stream>>>(xb, Wb, qkv, 3072, 2048, 12, tab);
  vtrans<<<256, 256, 0, stream>>>(qkv, vt);
  attn_fwd<<<256, 512, 0, stream>>>(qkv, vt, yb);
  gemm_bt<float><<<512, 256, 0, stream>>>(yb, Wpb, out, 2048, 2048, 16);
}

// Round 12
// 183.578 us; speedup vs baseline: 1.0710x; 1.0710x over previous
//
#include <hip/hip_runtime.h>

// ---------------------------------------------------------------------------
// SelfAttention fused pipeline for MI355X (gfx950)
// B=4 S=1024 DIM=2048 H=16 KV=4 HD=128 ROPE_DIM=64
//
// Stages (all on `stream`), 5 launches:
//  1) prep: casts fp32->bf16 (x | Wq|Wk|Wv | Wproj) + rope cos/sin table
//  2) gemm_bt<FUSE>: qkv = xb @ Wcat^T (128^2, TRIPLE-buffered counted-vmcnt
//     pipeline, swizzled LDS) + fused RMSNorm/RoPE/log2-prescale epilogue
//  3) vtrans: V -> Vt_global[b,kvh][d][kv] (pre-swizzled for LDS staging)
//  4) attn_fwd: causal flash attention + v-proj correction -> y bf16
//  5) gemm_bt: out = y @ Wproj^T (fp32 out)
// ---------------------------------------------------------------------------

typedef __attribute__((ext_vector_type(8))) __bf16 bf16x8;
typedef __attribute__((ext_vector_type(4))) __bf16 bf16x4;
typedef __attribute__((ext_vector_type(4))) float f32x4;

static_assert(sizeof(__bf16) == 2, "bf16 size");

#define MFMA16x16x32(a, b, c) __builtin_amdgcn_mfma_f32_16x16x32_bf16((a), (b), (c), 0, 0, 0)

#if __has_builtin(__builtin_amdgcn_exp2f)
#define EXP2(x) __builtin_amdgcn_exp2f(x)
#else
#define EXP2(x) exp2f(x)
#endif

__device__ __forceinline__ void gload_lds16(const void* g, void* l) {
  __builtin_amdgcn_global_load_lds((const __attribute__((address_space(1))) void*)g,
                                   (__attribute__((address_space(3))) void*)l, 16, 0, 0);
}

// ---------------- 1) prep: all casts + rope table, one kernel ----------------
__global__ __launch_bounds__(256) void prep(const float* __restrict__ x,
                                            const float* __restrict__ wq,
                                            const float* __restrict__ wk,
                                            const float* __restrict__ wv,
                                            const float* __restrict__ wp,
                                            __bf16* __restrict__ xb,
                                            __bf16* __restrict__ wb,
                                            __bf16* __restrict__ wpb,
                                            float2* __restrict__ tab) {
  constexpr int NX = 2097152;   // 4096*2048/4
  constexpr int NW1 = 1048576;  // 2048*2048/4
  constexpr int NW2 = 262144;   // 512*2048/4
  constexpr int NP = 1048576;   // 2048*2048/4
  constexpr int NT = 32768;     // 1024*32 rope table entries
  constexpr int TOT = NX + NW1 + 2 * NW2 + NP + NT;
  auto cast4 = [](const float* s, __bf16* d, int i) {
    f32x4 v = ((const f32x4*)s)[i];
    bf16x4 o;
    o[0] = (__bf16)v[0];
    o[1] = (__bf16)v[1];
    o[2] = (__bf16)v[2];
    o[3] = (__bf16)v[3];
    ((bf16x4*)d)[i] = o;
  };
  int i = blockIdx.x * blockDim.x + threadIdx.x;
  const int stride = gridDim.x * blockDim.x;
  for (; i < TOT; i += stride) {
    int j = i;
    if (j < NX) {
      cast4(x, xb, j);
    } else if ((j -= NX) < NW1) {
      cast4(wq, wb, j);
    } else if ((j -= NW1) < NW2) {
      cast4(wk, wb + (size_t)NW1 * 4, j);
    } else if ((j -= NW2) < NW2) {
      cast4(wv, wb + (size_t)(NW1 + NW2) * 4, j);
    } else if ((j -= NW2) < NP) {
      cast4(wp, wpb, j);
    } else {
      j -= NP;  // rope table: entry (s, jj)
      const int s = j >> 5, jj = j & 31;
      const float inv = powf(10000.0f, -(float)jj * 0.03125f);
      const float ang = (float)s * inv;
      tab[j] = make_float2(cosf(ang), sinf(ang));
    }
  }
}

// ---------------- 2/5) B^T GEMM: 128^2, 3-buffer counted-vmcnt pipeline ------
// C[M,N] = A[M,K]*B[N,K]^T. 128x128 tile, BK=32, 4 waves (2x2) of 64x64.
// TRIPLE-buffered LDS (48 KB): iter kt stages tile kt+2, computes tile kt,
// then waits vmcnt(4) (= tile kt+1's 4 loads landed; kt+2's 4 stay in
// flight) before a RAW s_barrier -- loads get a full iteration (~1200cy) of
// cover instead of ~350cy (the R10 __syncthreads drained vmcnt to 0 against
// just-issued loads). Per-wave wait BEFORE barrier => after barrier all
// waves' kt+1 loads landed (RAW safe); buffer overwritten 2 iters after its
// reads were consumed by MFMAs pre-barrier (WAR safe).
// LDS col-group swizzled by (row>>1)&3 (R8-verified 0 conflicts) via
// inverse-swizzled global source. 1-D grid, XCD-chunked, bm-major in chunk.
// FUSE epilogue (QKV only): 128-col tile = one q/k head -> RMSNorm + partial
// RoPE + q log2-domain prescale.
template <typename CT, bool FUSE>
__global__ __launch_bounds__(256) void gemm_bt(const __bf16* __restrict__ A,
                                               const __bf16* __restrict__ B,
                                               CT* __restrict__ C, int N, int K, int nbn,
                                               const float2* __restrict__ tab) {
  __shared__ __bf16 As[3][128 * 32];
  __shared__ __bf16 Bs[3][128 * 32];
  const int nwg = gridDim.x;
  const int id = blockIdx.x;
  const int xid = (id & 7) * (nwg >> 3) + (id >> 3);
  const int bm = xid / nbn;
  const int bn = xid - bm * nbn;
  const int t = threadIdx.x;
  const int l = t & 63, w = t >> 6;
  const int wr = w >> 1, wc = w & 1;
  const int lr = l & 15, lk = l >> 4;
  const __bf16* Ab = A + (size_t)bm * 128 * K;
  const __bf16* Bb = B + (size_t)bn * 128 * K;
  const int srow = t >> 2;                              // 0..63 (also +64)
  const int scol = ((t & 3) ^ ((srow >> 1) & 3)) << 3;  // inverse swizzle on src
  f32x4 acc[4][4] = {};

  auto stage = [&](int kt, int buf) {
    const int k0 = kt << 5;
    gload_lds16(Ab + (size_t)srow * K + k0 + scol, &As[buf][t * 8]);
    gload_lds16(Ab + (size_t)(srow + 64) * K + k0 + scol, &As[buf][2048 + t * 8]);
    gload_lds16(Bb + (size_t)srow * K + k0 + scol, &Bs[buf][t * 8]);
    gload_lds16(Bb + (size_t)(srow + 64) * K + k0 + scol, &Bs[buf][2048 + t * 8]);
  };

  // prologue: tiles 0,1 in flight; wait tile 0 only (tile 1 stays out)
  stage(0, 0);
  stage(1, 1);
  asm volatile("s_waitcnt vmcnt(4)" ::: "memory");
  __builtin_amdgcn_s_barrier();

  const int NT = K >> 5;
  int cur = 0;
  for (int kt = 0; kt < NT; ++kt) {
    if (kt + 2 < NT) {
      int c2 = cur + 2;
      if (c2 >= 3) c2 -= 3;
      stage(kt + 2, c2);  // issue 2-ahead (async)
    }

    bf16x8 af[4], bfr[4];
#pragma unroll
    for (int m = 0; m < 4; ++m) {
      const int row = wr * 64 + m * 16 + lr;
      af[m] = *(const bf16x8*)&As[cur][row * 32 + ((lk ^ ((row >> 1) & 3)) << 3)];
    }
#pragma unroll
    for (int n = 0; n < 4; ++n) {
      const int row = wc * 64 + n * 16 + lr;
      bfr[n] = *(const bf16x8*)&Bs[cur][row * 32 + ((lk ^ ((row >> 1) & 3)) << 3)];
    }
#pragma unroll
    for (int m = 0; m < 4; ++m)
#pragma unroll
      for (int n = 0; n < 4; ++n) acc[m][n] = MFMA16x16x32(af[m], bfr[n], acc[m][n]);

    // counted wait: tile kt+1 landed (kt+2's loads remain in flight)
    if (kt + 2 < NT)
      asm volatile("s_waitcnt vmcnt(4)" ::: "memory");
    else
      asm volatile("s_waitcnt vmcnt(0)" ::: "memory");
    __builtin_amdgcn_s_barrier();

    ++cur;
    if (cur == 3) cur = 0;
  }

  if constexpr (FUSE) {
    // bn 0..15 = q heads, 16..19 = k heads, 20..23 = v (plain store)
    if (bn < 20) {
      __syncthreads();  // full drain before LDS reuse
      __shared__ float Ls[2][128];
      float ssp[4][4];
#pragma unroll
      for (int m = 0; m < 4; ++m)
#pragma unroll
        for (int i = 0; i < 4; ++i) {
          float s = 0.0f;
#pragma unroll
          for (int n = 0; n < 4; ++n) s += acc[m][n][i] * acc[m][n][i];
#pragma unroll
          for (int off = 1; off < 16; off <<= 1) s += __shfl_xor(s, off);
          ssp[m][i] = s;
        }
      if (lr == 0) {
#pragma unroll
        for (int m = 0; m < 4; ++m)
#pragma unroll
          for (int i = 0; i < 4; ++i)
            Ls[wc][wr * 64 + m * 16 + lk * 4 + i] = ssp[m][i];
      }
      __syncthreads();
      const bool isq = (bn < 16);
      const float qs = isq ? 0.1275174457f : 1.0f;  // (1/sqrt(128))*log2(e)
#pragma unroll
      for (int m = 0; m < 4; ++m) {
#pragma unroll
        for (int i = 0; i < 4; ++i) {
          const int rl = wr * 64 + m * 16 + lk * 4 + i;
          const int rg = bm * 128 + rl;
          const float sc =
              rsqrtf((Ls[0][rl] + Ls[1][rl]) * (1.0f / 128.0f) +
                     1.1920928955078125e-07f) *
              qs;
          CT* Cr = C + (size_t)rg * N + bn * 128;
          if (wc == 0) {
            const int s = rg & 1023;
#pragma unroll
            for (int n = 0; n < 2; ++n) {
              const int j = n * 16 + lr;
              const float2 cs = tab[s * 32 + j];
              const float x1 = acc[m][n][i], x2 = acc[m][n + 2][i];
              Cr[j] = (CT)((x1 * cs.x + x2 * cs.y) * sc);
              Cr[j + 32] = (CT)((-x1 * cs.y + x2 * cs.x) * sc);
            }
          } else {
#pragma unroll
            for (int n = 0; n < 4; ++n)
              Cr[64 + n * 16 + lr] = (CT)(acc[m][n][i] * sc);
          }
        }
      }
      return;
    }
  }

#pragma unroll
  for (int m = 0; m < 4; ++m) {
    const int row0 = bm * 128 + wr * 64 + m * 16 + lk * 4;
#pragma unroll
    for (int n = 0; n < 4; ++n) {
      const int col = bn * 128 + wc * 64 + n * 16 + lr;
#pragma unroll
      for (int i = 0; i < 4; ++i) C[(size_t)(row0 + i) * N + col] = (CT)acc[m][n][i];
    }
  }
}

// ---------------- 3) V transpose: Vt[b,kvh][d][kv ^ ((d&7)<<3)] -------------
__global__ __launch_bounds__(256) void vtrans(const __bf16* __restrict__ qkv,
                                              __bf16* __restrict__ vt) {
  __shared__ __bf16 L[64 * 128];
  const int tile = blockIdx.x;  // (b*4+kvh)*16 + st
  const int st = tile & 15, bk = tile >> 4;
  const int b = bk >> 2, kvh = bk & 3;
  const int t = threadIdx.x;
  const int s0 = st * 64;
  const __bf16* src = qkv + ((size_t)(b * 1024 + s0)) * 3072 + 2560 + kvh * 128;
#pragma unroll
  for (int r = 0; r < 4; ++r) {
    const int off = r * 2048 + t * 8;
    const int s = off >> 7, d = off & 127;
    bf16x8 v = *(const bf16x8*)(src + (size_t)s * 3072 + d);
    *(bf16x8*)&L[s * 128 + (d ^ ((s & 7) << 3) ^ (((s >> 3) & 7) << 3))] = v;
  }
  __syncthreads();
  __bf16* dst = vt + (size_t)bk * 128 * 1024;
#pragma unroll
  for (int r = 0; r < 4; ++r) {
    const int off = r * 2048 + t * 8;
    const int d = off >> 6, sc = off & 63;
    bf16x8 v;
#pragma unroll
    for (int j = 0; j < 8; ++j) {
      const int s = sc + j;
      v[j] = L[s * 128 + (d ^ ((s & 7) << 3) ^ (((s >> 3) & 7) << 3))];
    }
    *(bf16x8*)&dst[(size_t)d * 1024 + ((s0 + sc) ^ ((d & 7) << 3))] = v;
  }
}

// ---------------- 4) causal flash attention + v-projection correction ------
// 256 blocks (=1/CU), each handles ONE (b,h) and TWO q-tiles (pr, 7-pr)
// sequentially -> exactly 18 kv-iterations/block. XCD grouping: blocks of one
// (b,kvh) group share an XCD (id&7) so K/V stays L2-resident.
__global__ __launch_bounds__(512) void attn_fwd(const __bf16* __restrict__ qkv,
                                                const __bf16* __restrict__ vt,
                                                __bf16* __restrict__ y) {
  const int id = blockIdx.x;
  const int g = (id & 7) | (((id >> 3) & 1) << 3);  // (b,kvh) group 0..15
  const int b = g >> 2, kvh = g & 3;
  const int hi = (id >> 4) & 3;
  const int pr = (id >> 6) & 3;
  const int h = kvh * 4 + hi;

  const int t = threadIdx.x;
  const int l = t & 63, w = t >> 6;  // 8 waves
  const int lr = l & 15, lk = l >> 4;
  const int lr8 = lr & 7;

  __shared__ __bf16 Ks[2][64 * 128];
  __shared__ __bf16 Vs[2][128 * 64];
  __shared__ __bf16 Ps[8][16 * 64];

  const size_t rb = (size_t)b * 1024;
  const __bf16* Kg0 = qkv + rb * 3072 + 2048 + kvh * 128;
  const __bf16* Vtb = vt + (size_t)(b * 4 + kvh) * 128 * 1024;

  const int koff0 = t * 8;
  const int krow0 = koff0 >> 7;
  const int kcol0 = (koff0 & 127) ^ ((krow0 & 7) << 3);
  const int koff1 = 4096 + t * 8;
  const int krow1 = koff1 >> 7;
  const int kcol1 = (koff1 & 127) ^ ((krow1 & 7) << 3);
  const int voff0 = t * 8, voff1 = 4096 + t * 8;

#pragma unroll 1
  for (int pass = 0; pass < 2; ++pass) {
    const int qt = pass ? (7 - pr) : pr;
    const int q0 = qt << 7;

    bf16x8 aq[4];
    {
      const __bf16* qrow = qkv + (rb + q0 + w * 16 + lr) * 3072 + h * 128 + lk * 8;
#pragma unroll
      for (int kk = 0; kk < 4; ++kk) aq[kk] = *(const bf16x8*)(qrow + kk * 32);
    }

    float m_i[4], l_i[4];
    f32x4 o[8] = {};
#pragma unroll
    for (int i = 0; i < 4; ++i) {
      m_i[i] = -1e30f;
      l_i[i] = 0.0f;
    }

    const int rowg0 = q0 + w * 16 + lk * 4;
    const int wmin = q0 + w * 16;
    const int wmax = wmin + 15;
    const int nt = 2 * qt + 2;

    gload_lds16(Kg0 + (size_t)krow0 * 3072 + kcol0, &Ks[0][0] + koff0);
    gload_lds16(Kg0 + (size_t)krow1 * 3072 + kcol1, &Ks[0][0] + koff1);
    gload_lds16(Vtb + (size_t)(voff0 >> 6) * 1024 + (voff0 & 63), &Vs[0][0] + voff0);
    gload_lds16(Vtb + (size_t)(voff1 >> 6) * 1024 + (voff1 & 63), &Vs[0][0] + voff1);
    __syncthreads();

    for (int tt = 0; tt < nt; ++tt) {
      const int kv0 = tt * 64;
      const int cur = tt & 1;
      if (tt + 1 < nt) {
        const int nkv = kv0 + 64;
        const __bf16* Kg = Kg0 + (size_t)nkv * 3072;
        __bf16* kd = &Ks[cur ^ 1][0];
        __bf16* vd = &Vs[cur ^ 1][0];
        gload_lds16(Kg + (size_t)krow0 * 3072 + kcol0, kd + koff0);
        gload_lds16(Kg + (size_t)krow1 * 3072 + kcol1, kd + koff1);
        gload_lds16(Vtb + (size_t)(voff0 >> 6) * 1024 + nkv + (voff0 & 63), vd + voff0);
        gload_lds16(Vtb + (size_t)(voff1 >> 6) * 1024 + nkv + (voff1 & 63), vd + voff1);
      }

      if (kv0 <= wmax) {
        f32x4 sacc[4] = {};
        __builtin_amdgcn_s_setprio(1);
#pragma unroll
        for (int kk = 0; kk < 4; ++kk) {
#pragma unroll
          for (int n = 0; n < 4; ++n) {
            const bf16x8 bk = *(const bf16x8*)&Ks[cur][(n * 16 + lr) * 128 +
                                                      ((kk * 32 + lk * 8) ^ (lr8 << 3))];
            sacc[n] = MFMA16x16x32(aq[kk], bk, sacc[n]);
          }
        }
        __builtin_amdgcn_s_setprio(0);

        float pm[4];
#pragma unroll
        for (int i = 0; i < 4; ++i) pm[i] = -1e30f;
        if (kv0 + 63 > wmin) {
#pragma unroll
          for (int n = 0; n < 4; ++n) {
            const int colg = kv0 + n * 16 + lr;
#pragma unroll
            for (int i = 0; i < 4; ++i) {
              if (colg > rowg0 + i) sacc[n][i] = -1e30f;
              pm[i] = fmaxf(pm[i], sacc[n][i]);
            }
          }
        } else {
#pragma unroll
          for (int n = 0; n < 4; ++n)
#pragma unroll
            for (int i = 0; i < 4; ++i) pm[i] = fmaxf(pm[i], sacc[n][i]);
        }
#pragma unroll
        for (int i = 0; i < 4; ++i) {
          pm[i] = fmaxf(pm[i], __shfl_xor(pm[i], 1));
          pm[i] = fmaxf(pm[i], __shfl_xor(pm[i], 2));
          pm[i] = fmaxf(pm[i], __shfl_xor(pm[i], 4));
          pm[i] = fmaxf(pm[i], __shfl_xor(pm[i], 8));
        }
        float alpha[4], rs[4];
#pragma unroll
        for (int i = 0; i < 4; ++i) {
          const float mn = fmaxf(m_i[i], pm[i]);
          alpha[i] = EXP2(m_i[i] - mn);
          m_i[i] = mn;
          rs[i] = 0.0f;
        }
#pragma unroll
        for (int n = 0; n < 4; ++n) {
#pragma unroll
          for (int i = 0; i < 4; ++i) {
            const float p = EXP2(sacc[n][i] - m_i[i]);
            rs[i] += p;
            const int prow = lk * 4 + i;
            Ps[w][prow * 64 + ((n * 16 + lr) ^ ((prow & 7) << 3))] = (__bf16)p;
          }
        }
#pragma unroll
        for (int i = 0; i < 4; ++i) {
          rs[i] += __shfl_xor(rs[i], 1);
          rs[i] += __shfl_xor(rs[i], 2);
          rs[i] += __shfl_xor(rs[i], 4);
          rs[i] += __shfl_xor(rs[i], 8);
          l_i[i] = l_i[i] * alpha[i] + rs[i];
        }
#pragma unroll
        for (int f = 0; f < 8; ++f)
#pragma unroll
          for (int i = 0; i < 4; ++i) o[f][i] *= alpha[i];

        __builtin_amdgcn_s_setprio(1);
#pragma unroll
        for (int ks = 0; ks < 2; ++ks) {
          const bf16x8 pa =
              *(const bf16x8*)&Ps[w][lr * 64 + ((ks * 32 + lk * 8) ^ (lr8 << 3))];
#pragma unroll
          for (int f = 0; f < 8; ++f) {
            const bf16x8 vb = *(const bf16x8*)&Vs[cur][(f * 16 + lr) * 64 +
                                                       ((ks * 32 + lk * 8) ^ (lr8 << 3))];
            o[f] = MFMA16x16x32(pa, vb, o[f]);
          }
        }
        __builtin_amdgcn_s_setprio(0);
      }

      __syncthreads();
    }

#pragma unroll
    for (int i = 0; i < 4; ++i) {
      const int sg = rowg0 + i;
      const size_t mg = rb + sg;
      const __bf16* vp = qkv + mg * 3072 + 2560 + kvh * 128;
      const float invl = 1.0f / l_i[i];
      float vvv[8], yvv[8];
      float dyv = 0.0f, dvv = 0.0f;
#pragma unroll
      for (int f = 0; f < 8; ++f) {
        const float vf = (float)vp[f * 16 + lr];
        const float yf = o[f][i] * invl;
        vvv[f] = vf;
        yvv[f] = yf;
        dyv += yf * vf;
        dvv += vf * vf;
      }
#pragma unroll
      for (int off = 1; off < 16; off <<= 1) {
        dyv += __shfl_xor(dyv, off);
        dvv += __shfl_xor(dvv, off);
      }
      const float proj = dyv / fmaxf(dvv, 1e-6f);
      __bf16* yp = y + mg * 2048 + h * 128;
#pragma unroll
      for (int f = 0; f < 8; ++f) yp[f * 16 + lr] = (__bf16)(yvv[f] - proj * vvv[f]);
    }
  }
}

// ---------------------------------------------------------------------------
extern "C" void kernel_launch(void* const* d_in, const int* in_sizes, int n_in,
                              void* d_out, int out_size, void* d_ws, size_t ws_size,
                              hipStream_t stream) {
  const float* x = (const float*)d_in[0];
  const float* Wq = (const float*)d_in[2];
  const float* Wk = (const float*)d_in[3];
  const float* Wv = (const float*)d_in[4];
  const float* Wp = (const float*)d_in[5];
  float* out = (float*)d_out;

  __bf16* xb = (__bf16*)d_ws;                // 4096x2048
  __bf16* Wb = xb + (size_t)4096 * 2048;     // 3072x2048  [Wq;Wk;Wv]
  __bf16* Wpb = Wb + (size_t)3072 * 2048;    // 2048x2048
  __bf16* qkv = Wpb + (size_t)2048 * 2048;   // 4096x3072
  __bf16* yb = qkv + (size_t)4096 * 3072;    // 4096x2048
  float2* tab = (float2*)(yb + (size_t)4096 * 2048);  // 1024x32 cos/sin
  __bf16* vt = xb;  // reuse xb region after qkv GEMM (4*4*128*1024 elems)

  prep<<<2048, 256, 0, stream>>>(x, Wq, Wk, Wv, Wp, xb, Wb, Wpb, tab);

  gemm_bt<__bf16, true><<<768, 256, 0, stream>>>(xb, Wb, qkv, 3072, 2048, 24, tab);
  vtrans<<<256, 256, 0, stream>>>(qkv, vt);
  attn_fwd<<<256, 512, 0, stream>>>(qkv, vt, yb);
  gemm_bt<float, false><<<512, 256, 0, stream>>>(yb, Wpb, out, 2048, 2048, 16, nullptr);
}

// Round 13
// 182.974 us; speedup vs baseline: 1.0745x; 1.0033x over previous
//
#include <hip/hip_runtime.h>

// ---------------------------------------------------------------------------
// SelfAttention fused pipeline for MI355X (gfx950)
// B=4 S=1024 DIM=2048 H=16 KV=4 HD=128 ROPE_DIM=64
//
// Stages (all on `stream`), 5 launches:
//  1) prep: casts fp32->bf16 (x | Wq|Wk|Wv | Wproj) + rope cos/sin table
//  2) gemm_bt<FUSE>: qkv = xb @ Wcat^T (128^2, 3-buffer counted-vmcnt,
//     swizzled LDS) + fused RMSNorm/RoPE/log2-prescale epilogue
//  3) vtrans: V -> Vt_global[b,kvh][d][kv] (pre-swizzled for LDS staging)
//  4) attn_fwd: causal flash attention + v-proj correction -> y bf16
//     CONCURRENT-PAIR: 256 blocks x 1024 threads; waves 0-7 run heavy
//     q-tile (7-pr), waves 8-15 light q-tile (pr), sharing one K/V
//     staging stream (heavy range superset of light's). 16 waves/CU.
//  5) gemm_bt: out = y @ Wproj^T (fp32 out)
// ---------------------------------------------------------------------------

typedef __attribute__((ext_vector_type(8))) __bf16 bf16x8;
typedef __attribute__((ext_vector_type(4))) __bf16 bf16x4;
typedef __attribute__((ext_vector_type(4))) float f32x4;

static_assert(sizeof(__bf16) == 2, "bf16 size");

#define MFMA16x16x32(a, b, c) __builtin_amdgcn_mfma_f32_16x16x32_bf16((a), (b), (c), 0, 0, 0)

#if __has_builtin(__builtin_amdgcn_exp2f)
#define EXP2(x) __builtin_amdgcn_exp2f(x)
#else
#define EXP2(x) exp2f(x)
#endif

__device__ __forceinline__ void gload_lds16(const void* g, void* l) {
  __builtin_amdgcn_global_load_lds((const __attribute__((address_space(1))) void*)g,
                                   (__attribute__((address_space(3))) void*)l, 16, 0, 0);
}

// ---------------- 1) prep: all casts + rope table, one kernel ----------------
__global__ __launch_bounds__(256) void prep(const float* __restrict__ x,
                                            const float* __restrict__ wq,
                                            const float* __restrict__ wk,
                                            const float* __restrict__ wv,
                                            const float* __restrict__ wp,
                                            __bf16* __restrict__ xb,
                                            __bf16* __restrict__ wb,
                                            __bf16* __restrict__ wpb,
                                            float2* __restrict__ tab) {
  constexpr int NX = 2097152;   // 4096*2048/4
  constexpr int NW1 = 1048576;  // 2048*2048/4
  constexpr int NW2 = 262144;   // 512*2048/4
  constexpr int NP = 1048576;   // 2048*2048/4
  constexpr int NT = 32768;     // 1024*32 rope table entries
  constexpr int TOT = NX + NW1 + 2 * NW2 + NP + NT;
  auto cast4 = [](const float* s, __bf16* d, int i) {
    f32x4 v = ((const f32x4*)s)[i];
    bf16x4 o;
    o[0] = (__bf16)v[0];
    o[1] = (__bf16)v[1];
    o[2] = (__bf16)v[2];
    o[3] = (__bf16)v[3];
    ((bf16x4*)d)[i] = o;
  };
  int i = blockIdx.x * blockDim.x + threadIdx.x;
  const int stride = gridDim.x * blockDim.x;
  for (; i < TOT; i += stride) {
    int j = i;
    if (j < NX) {
      cast4(x, xb, j);
    } else if ((j -= NX) < NW1) {
      cast4(wq, wb, j);
    } else if ((j -= NW1) < NW2) {
      cast4(wk, wb + (size_t)NW1 * 4, j);
    } else if ((j -= NW2) < NW2) {
      cast4(wv, wb + (size_t)(NW1 + NW2) * 4, j);
    } else if ((j -= NW2) < NP) {
      cast4(wp, wpb, j);
    } else {
      j -= NP;  // rope table: entry (s, jj)
      const int s = j >> 5, jj = j & 31;
      const float inv = powf(10000.0f, -(float)jj * 0.03125f);
      const float ang = (float)s * inv;
      tab[j] = make_float2(cosf(ang), sinf(ang));
    }
  }
}

// ---------------- 2/5) B^T GEMM: 128^2, 3-buffer counted-vmcnt pipeline ------
// (R12 structure, measured equal-best: MfmaUtil ~29, conflicts 0.)
template <typename CT, bool FUSE>
__global__ __launch_bounds__(256) void gemm_bt(const __bf16* __restrict__ A,
                                               const __bf16* __restrict__ B,
                                               CT* __restrict__ C, int N, int K, int nbn,
                                               const float2* __restrict__ tab) {
  __shared__ __bf16 As[3][128 * 32];
  __shared__ __bf16 Bs[3][128 * 32];
  const int nwg = gridDim.x;
  const int id = blockIdx.x;
  const int xid = (id & 7) * (nwg >> 3) + (id >> 3);
  const int bm = xid / nbn;
  const int bn = xid - bm * nbn;
  const int t = threadIdx.x;
  const int l = t & 63, w = t >> 6;
  const int wr = w >> 1, wc = w & 1;
  const int lr = l & 15, lk = l >> 4;
  const __bf16* Ab = A + (size_t)bm * 128 * K;
  const __bf16* Bb = B + (size_t)bn * 128 * K;
  const int srow = t >> 2;                              // 0..63 (also +64)
  const int scol = ((t & 3) ^ ((srow >> 1) & 3)) << 3;  // inverse swizzle on src
  f32x4 acc[4][4] = {};

  auto stage = [&](int kt, int buf) {
    const int k0 = kt << 5;
    gload_lds16(Ab + (size_t)srow * K + k0 + scol, &As[buf][t * 8]);
    gload_lds16(Ab + (size_t)(srow + 64) * K + k0 + scol, &As[buf][2048 + t * 8]);
    gload_lds16(Bb + (size_t)srow * K + k0 + scol, &Bs[buf][t * 8]);
    gload_lds16(Bb + (size_t)(srow + 64) * K + k0 + scol, &Bs[buf][2048 + t * 8]);
  };

  stage(0, 0);
  stage(1, 1);
  asm volatile("s_waitcnt vmcnt(4)" ::: "memory");
  __builtin_amdgcn_s_barrier();

  const int NT = K >> 5;
  int cur = 0;
  for (int kt = 0; kt < NT; ++kt) {
    if (kt + 2 < NT) {
      int c2 = cur + 2;
      if (c2 >= 3) c2 -= 3;
      stage(kt + 2, c2);  // issue 2-ahead (async)
    }

    bf16x8 af[4], bfr[4];
#pragma unroll
    for (int m = 0; m < 4; ++m) {
      const int row = wr * 64 + m * 16 + lr;
      af[m] = *(const bf16x8*)&As[cur][row * 32 + ((lk ^ ((row >> 1) & 3)) << 3)];
    }
#pragma unroll
    for (int n = 0; n < 4; ++n) {
      const int row = wc * 64 + n * 16 + lr;
      bfr[n] = *(const bf16x8*)&Bs[cur][row * 32 + ((lk ^ ((row >> 1) & 3)) << 3)];
    }
#pragma unroll
    for (int m = 0; m < 4; ++m)
#pragma unroll
      for (int n = 0; n < 4; ++n) acc[m][n] = MFMA16x16x32(af[m], bfr[n], acc[m][n]);

    if (kt + 2 < NT)
      asm volatile("s_waitcnt vmcnt(4)" ::: "memory");
    else
      asm volatile("s_waitcnt vmcnt(0)" ::: "memory");
    __builtin_amdgcn_s_barrier();

    ++cur;
    if (cur == 3) cur = 0;
  }

  if constexpr (FUSE) {
    // bn 0..15 = q heads, 16..19 = k heads, 20..23 = v (plain store)
    if (bn < 20) {
      __syncthreads();  // full drain before LDS reuse
      __shared__ float Ls[2][128];
      float ssp[4][4];
#pragma unroll
      for (int m = 0; m < 4; ++m)
#pragma unroll
        for (int i = 0; i < 4; ++i) {
          float s = 0.0f;
#pragma unroll
          for (int n = 0; n < 4; ++n) s += acc[m][n][i] * acc[m][n][i];
#pragma unroll
          for (int off = 1; off < 16; off <<= 1) s += __shfl_xor(s, off);
          ssp[m][i] = s;
        }
      if (lr == 0) {
#pragma unroll
        for (int m = 0; m < 4; ++m)
#pragma unroll
          for (int i = 0; i < 4; ++i)
            Ls[wc][wr * 64 + m * 16 + lk * 4 + i] = ssp[m][i];
      }
      __syncthreads();
      const bool isq = (bn < 16);
      const float qs = isq ? 0.1275174457f : 1.0f;  // (1/sqrt(128))*log2(e)
#pragma unroll
      for (int m = 0; m < 4; ++m) {
#pragma unroll
        for (int i = 0; i < 4; ++i) {
          const int rl = wr * 64 + m * 16 + lk * 4 + i;
          const int rg = bm * 128 + rl;
          const float sc =
              rsqrtf((Ls[0][rl] + Ls[1][rl]) * (1.0f / 128.0f) +
                     1.1920928955078125e-07f) *
              qs;
          CT* Cr = C + (size_t)rg * N + bn * 128;
          if (wc == 0) {
            const int s = rg & 1023;
#pragma unroll
            for (int n = 0; n < 2; ++n) {
              const int j = n * 16 + lr;
              const float2 cs = tab[s * 32 + j];
              const float x1 = acc[m][n][i], x2 = acc[m][n + 2][i];
              Cr[j] = (CT)((x1 * cs.x + x2 * cs.y) * sc);
              Cr[j + 32] = (CT)((-x1 * cs.y + x2 * cs.x) * sc);
            }
          } else {
#pragma unroll
            for (int n = 0; n < 4; ++n)
              Cr[64 + n * 16 + lr] = (CT)(acc[m][n][i] * sc);
          }
        }
      }
      return;
    }
  }

#pragma unroll
  for (int m = 0; m < 4; ++m) {
    const int row0 = bm * 128 + wr * 64 + m * 16 + lk * 4;
#pragma unroll
    for (int n = 0; n < 4; ++n) {
      const int col = bn * 128 + wc * 64 + n * 16 + lr;
#pragma unroll
      for (int i = 0; i < 4; ++i) C[(size_t)(row0 + i) * N + col] = (CT)acc[m][n][i];
    }
  }
}

// ---------------- 3) V transpose: Vt[b,kvh][d][kv ^ ((d&7)<<3)] -------------
__global__ __launch_bounds__(256) void vtrans(const __bf16* __restrict__ qkv,
                                              __bf16* __restrict__ vt) {
  __shared__ __bf16 L[64 * 128];
  const int tile = blockIdx.x;  // (b*4+kvh)*16 + st
  const int st = tile & 15, bk = tile >> 4;
  const int b = bk >> 2, kvh = bk & 3;
  const int t = threadIdx.x;
  const int s0 = st * 64;
  const __bf16* src = qkv + ((size_t)(b * 1024 + s0)) * 3072 + 2560 + kvh * 128;
#pragma unroll
  for (int r = 0; r < 4; ++r) {
    const int off = r * 2048 + t * 8;
    const int s = off >> 7, d = off & 127;
    bf16x8 v = *(const bf16x8*)(src + (size_t)s * 3072 + d);
    *(bf16x8*)&L[s * 128 + (d ^ ((s & 7) << 3) ^ (((s >> 3) & 7) << 3))] = v;
  }
  __syncthreads();
  __bf16* dst = vt + (size_t)bk * 128 * 1024;
#pragma unroll
  for (int r = 0; r < 4; ++r) {
    const int off = r * 2048 + t * 8;
    const int d = off >> 6, sc = off & 63;
    bf16x8 v;
#pragma unroll
    for (int j = 0; j < 8; ++j) {
      const int s = sc + j;
      v[j] = L[s * 128 + (d ^ ((s & 7) << 3) ^ (((s >> 3) & 7) << 3))];
    }
    *(bf16x8*)&dst[(size_t)d * 1024 + ((s0 + sc) ^ ((d & 7) << 3))] = v;
  }
}

// ---------------- 4) causal flash attention + v-projection correction ------
// CONCURRENT-PAIR: 256 blocks (=1/CU) x 1024 threads (16 waves). Waves 0-7
// process heavy q-tile (7-pr), waves 8-15 light q-tile (pr) of one (b,h).
// Heavy kv-range (16-2pr tiles) is a superset of light's (2pr+2) -> ONE
// shared double-buffered K/V staging stream; light waves skip compute past
// their diagonal. 1024 threads stage a 16KB tile in ONE gload_lds16 each.
// In-block balance guaranteed; 16 waves/CU hides latency (2x prior).
// XCD grouping: blocks of one (b,kvh) group share an XCD (id&7).
__global__ __launch_bounds__(1024) void attn_fwd(const __bf16* __restrict__ qkv,
                                                 const __bf16* __restrict__ vt,
                                                 __bf16* __restrict__ y) {
  const int id = blockIdx.x;
  const int g = (id & 7) | (((id >> 3) & 1) << 3);  // (b,kvh) group 0..15
  const int b = g >> 2, kvh = g & 3;
  const int hi = (id >> 4) & 3;
  const int pr = (id >> 6) & 3;
  const int h = kvh * 4 + hi;

  const int t = threadIdx.x;
  const int l = t & 63, w = t >> 6;  // 16 waves
  const int lr = l & 15, lk = l >> 4;
  const int lr8 = lr & 7;
  const int w8 = w & 7;

  __shared__ __bf16 Ks[2][64 * 128];
  __shared__ __bf16 Vs[2][128 * 64];
  __shared__ __bf16 Ps[16][16 * 64];

  const size_t rb = (size_t)b * 1024;
  const __bf16* Kg0 = qkv + rb * 3072 + 2048 + kvh * 128;
  const __bf16* Vtb = vt + (size_t)(b * 4 + kvh) * 128 * 1024;

  // staging: 1024 threads cover the 64x128 K tile / 128x64 V^T tile with
  // one 16B gload each
  const int koff = t * 8;
  const int krow = koff >> 7;
  const int kcol = (koff & 127) ^ ((krow & 7) << 3);
  const int voff = t * 8;

  // wave -> q-tile: waves 0-7 heavy (7-pr), 8-15 light (pr)
  const int qt = (w < 8) ? (7 - pr) : pr;
  const int q0 = qt << 7;

  // Q fragments -> registers; wave owns q-rows q0 + w8*16 .. +15
  bf16x8 aq[4];
  {
    const __bf16* qrow = qkv + (rb + q0 + w8 * 16 + lr) * 3072 + h * 128 + lk * 8;
#pragma unroll
    for (int kk = 0; kk < 4; ++kk) aq[kk] = *(const bf16x8*)(qrow + kk * 32);
  }

  float m_i[4], l_i[4];
  f32x4 o[8] = {};
#pragma unroll
  for (int i = 0; i < 4; ++i) {
    m_i[i] = -1e30f;
    l_i[i] = 0.0f;
  }

  const int rowg0 = q0 + w8 * 16 + lk * 4;
  const int wmin = q0 + w8 * 16;
  const int wmax = wmin + 15;
  const int nt = 2 * (7 - pr) + 2;  // heavy range (superset of light's)

  // prologue: stage tile 0 into buf 0
  gload_lds16(Kg0 + (size_t)krow * 3072 + kcol, &Ks[0][0] + koff);
  gload_lds16(Vtb + (size_t)(voff >> 6) * 1024 + (voff & 63), &Vs[0][0] + voff);
  __syncthreads();  // drains vmcnt -> buf0 ready

  for (int tt = 0; tt < nt; ++tt) {
    const int kv0 = tt * 64;
    const int cur = tt & 1;
    // issue next tile's staging first (async; lands in other buffer)
    if (tt + 1 < nt) {
      const int nkv = kv0 + 64;
      gload_lds16(Kg0 + (size_t)(nkv + krow) * 3072 + kcol, &Ks[cur ^ 1][0] + koff);
      gload_lds16(Vtb + (size_t)(voff >> 6) * 1024 + nkv + (voff & 63),
                  &Vs[cur ^ 1][0] + voff);
    }

    if (kv0 <= wmax) {  // wave has unmasked work in this tile
      // S = Q K^T (log2-domain: q pre-scaled in gemm epilogue)
      f32x4 sacc[4] = {};
      __builtin_amdgcn_s_setprio(1);
#pragma unroll
      for (int kk = 0; kk < 4; ++kk) {
#pragma unroll
        for (int n = 0; n < 4; ++n) {
          const bf16x8 bk = *(const bf16x8*)&Ks[cur][(n * 16 + lr) * 128 +
                                                    ((kk * 32 + lk * 8) ^ (lr8 << 3))];
          sacc[n] = MFMA16x16x32(aq[kk], bk, sacc[n]);
        }
      }
      __builtin_amdgcn_s_setprio(0);

      // causal mask (diagonal tiles only) + online softmax (exp2)
      float pm[4];
#pragma unroll
      for (int i = 0; i < 4; ++i) pm[i] = -1e30f;
      if (kv0 + 63 > wmin) {
#pragma unroll
        for (int n = 0; n < 4; ++n) {
          const int colg = kv0 + n * 16 + lr;
#pragma unroll
          for (int i = 0; i < 4; ++i) {
            if (colg > rowg0 + i) sacc[n][i] = -1e30f;
            pm[i] = fmaxf(pm[i], sacc[n][i]);
          }
        }
      } else {
#pragma unroll
        for (int n = 0; n < 4; ++n)
#pragma unroll
          for (int i = 0; i < 4; ++i) pm[i] = fmaxf(pm[i], sacc[n][i]);
      }
#pragma unroll
      for (int i = 0; i < 4; ++i) {
        pm[i] = fmaxf(pm[i], __shfl_xor(pm[i], 1));
        pm[i] = fmaxf(pm[i], __shfl_xor(pm[i], 2));
        pm[i] = fmaxf(pm[i], __shfl_xor(pm[i], 4));
        pm[i] = fmaxf(pm[i], __shfl_xor(pm[i], 8));
      }
      float alpha[4], rs[4];
#pragma unroll
      for (int i = 0; i < 4; ++i) {
        const float mn = fmaxf(m_i[i], pm[i]);
        alpha[i] = EXP2(m_i[i] - mn);
        m_i[i] = mn;
        rs[i] = 0.0f;
      }
#pragma unroll
      for (int n = 0; n < 4; ++n) {
#pragma unroll
        for (int i = 0; i < 4; ++i) {
          const float p = EXP2(sacc[n][i] - m_i[i]);
          rs[i] += p;
          const int prow = lk * 4 + i;
          Ps[w][prow * 64 + ((n * 16 + lr) ^ ((prow & 7) << 3))] = (__bf16)p;
        }
      }
#pragma unroll
      for (int i = 0; i < 4; ++i) {
        rs[i] += __shfl_xor(rs[i], 1);
        rs[i] += __shfl_xor(rs[i], 2);
        rs[i] += __shfl_xor(rs[i], 4);
        rs[i] += __shfl_xor(rs[i], 8);
        l_i[i] = l_i[i] * alpha[i] + rs[i];
      }
#pragma unroll
      for (int f = 0; f < 8; ++f)
#pragma unroll
        for (int i = 0; i < 4; ++i) o[f][i] *= alpha[i];

      // O += P V
      __builtin_amdgcn_s_setprio(1);
#pragma unroll
      for (int ks = 0; ks < 2; ++ks) {
        const bf16x8 pa =
            *(const bf16x8*)&Ps[w][lr * 64 + ((ks * 32 + lk * 8) ^ (lr8 << 3))];
#pragma unroll
        for (int f = 0; f < 8; ++f) {
          const bf16x8 vb = *(const bf16x8*)&Vs[cur][(f * 16 + lr) * 64 +
                                                     ((ks * 32 + lk * 8) ^ (lr8 << 3))];
          o[f] = MFMA16x16x32(pa, vb, o[f]);
        }
      }
      __builtin_amdgcn_s_setprio(0);
    }

    __syncthreads();  // next tile staged (vmcnt drained) + all LDS reads done
  }

  // epilogue: normalize, v-projection correction, store bf16
#pragma unroll
  for (int i = 0; i < 4; ++i) {
    const int sg = rowg0 + i;
    const size_t mg = rb + sg;
    const __bf16* vp = qkv + mg * 3072 + 2560 + kvh * 128;
    const float invl = 1.0f / l_i[i];
    float vvv[8], yvv[8];
    float dyv = 0.0f, dvv = 0.0f;
#pragma unroll
    for (int f = 0; f < 8; ++f) {
      const float vf = (float)vp[f * 16 + lr];
      const float yf = o[f][i] * invl;
      vvv[f] = vf;
      yvv[f] = yf;
      dyv += yf * vf;
      dvv += vf * vf;
    }
#pragma unroll
    for (int off = 1; off < 16; off <<= 1) {
      dyv += __shfl_xor(dyv, off);
      dvv += __shfl_xor(dvv, off);
    }
    const float proj = dyv / fmaxf(dvv, 1e-6f);
    __bf16* yp = y + mg * 2048 + h * 128;
#pragma unroll
    for (int f = 0; f < 8; ++f) yp[f * 16 + lr] = (__bf16)(yvv[f] - proj * vvv[f]);
  }
}

// ---------------------------------------------------------------------------
extern "C" void kernel_launch(void* const* d_in, const int* in_sizes, int n_in,
                              void* d_out, int out_size, void* d_ws, size_t ws_size,
                              hipStream_t stream) {
  const float* x = (const float*)d_in[0];
  const float* Wq = (const float*)d_in[2];
  const float* Wk = (const float*)d_in[3];
  const float* Wv = (const float*)d_in[4];
  const float* Wp = (const float*)d_in[5];
  float* out = (float*)d_out;

  __bf16* xb = (__bf16*)d_ws;                // 4096x2048
  __bf16* Wb = xb + (size_t)4096 * 2048;     // 3072x2048  [Wq;Wk;Wv]
  __bf16* Wpb = Wb + (size_t)3072 * 2048;    // 2048x2048
  __bf16* qkv = Wpb + (size_t)2048 * 2048;   // 4096x3072
  __bf16* yb = qkv + (size_t)4096 * 3072;    // 4096x2048
  float2* tab = (float2*)(yb + (size_t)4096 * 2048);  // 1024x32 cos/sin
  __bf16* vt = xb;  // reuse xb region after qkv GEMM (4*4*128*1024 elems)

  prep<<<2048, 256, 0, stream>>>(x, Wq, Wk, Wv, Wp, xb, Wb, Wpb, tab);

  gemm_bt<__bf16, true><<<768, 256, 0, stream>>>(xb, Wb, qkv, 3072, 2048, 24, tab);
  vtrans<<<256, 256, 0, stream>>>(qkv, vt);
  attn_fwd<<<256, 1024, 0, stream>>>(qkv, vt, yb);
  gemm_bt<float, false><<<512, 256, 0, stream>>>(yb, Wpb, out, 2048, 2048, 16, nullptr);
}

// Round 14
// 178.723 us; speedup vs baseline: 1.1001x; 1.0238x over previous
//
#include <hip/hip_runtime.h>

// ---------------------------------------------------------------------------
// SelfAttention fused pipeline for MI355X (gfx950)
// B=4 S=1024 DIM=2048 H=16 KV=4 HD=128 ROPE_DIM=64
//
// Stages (all on `stream`), 5 launches:
//  1) prep: casts fp32->bf16 (x | Wq|Wk|Wv | Wproj) + rope cos/sin table
//  2) gemm_bt<FUSE>: qkv = xb @ Wcat^T (128^2, 3-buffer counted-vmcnt,
//     swizzled LDS) + fused RMSNorm/RoPE/log2-prescale epilogue
//  3) vtrans: V -> Vt_global[b,kvh][d][kv] (pre-swizzled for LDS staging)
//  4) attn_fwd: causal flash attention + v-proj correction -> y bf16
//     KVBLK=128 sequential-pair: 256 blocks x 512 thr; passes (7-pr, pr)
//     => exactly 9 kv-iterations/block (was 18), balanced; 160 KB LDS.
//  5) gemm_bt: out = y @ Wproj^T (fp32 out)
// ---------------------------------------------------------------------------

typedef __attribute__((ext_vector_type(8))) __bf16 bf16x8;
typedef __attribute__((ext_vector_type(4))) __bf16 bf16x4;
typedef __attribute__((ext_vector_type(4))) float f32x4;

static_assert(sizeof(__bf16) == 2, "bf16 size");

#define MFMA16x16x32(a, b, c) __builtin_amdgcn_mfma_f32_16x16x32_bf16((a), (b), (c), 0, 0, 0)

#if __has_builtin(__builtin_amdgcn_exp2f)
#define EXP2(x) __builtin_amdgcn_exp2f(x)
#else
#define EXP2(x) exp2f(x)
#endif

__device__ __forceinline__ void gload_lds16(const void* g, void* l) {
  __builtin_amdgcn_global_load_lds((const __attribute__((address_space(1))) void*)g,
                                   (__attribute__((address_space(3))) void*)l, 16, 0, 0);
}

// ---------------- 1) prep: all casts + rope table, one kernel ----------------
__global__ __launch_bounds__(256) void prep(const float* __restrict__ x,
                                            const float* __restrict__ wq,
                                            const float* __restrict__ wk,
                                            const float* __restrict__ wv,
                                            const float* __restrict__ wp,
                                            __bf16* __restrict__ xb,
                                            __bf16* __restrict__ wb,
                                            __bf16* __restrict__ wpb,
                                            float2* __restrict__ tab) {
  constexpr int NX = 2097152;   // 4096*2048/4
  constexpr int NW1 = 1048576;  // 2048*2048/4
  constexpr int NW2 = 262144;   // 512*2048/4
  constexpr int NP = 1048576;   // 2048*2048/4
  constexpr int NT = 32768;     // 1024*32 rope table entries
  constexpr int TOT = NX + NW1 + 2 * NW2 + NP + NT;
  auto cast4 = [](const float* s, __bf16* d, int i) {
    f32x4 v = ((const f32x4*)s)[i];
    bf16x4 o;
    o[0] = (__bf16)v[0];
    o[1] = (__bf16)v[1];
    o[2] = (__bf16)v[2];
    o[3] = (__bf16)v[3];
    ((bf16x4*)d)[i] = o;
  };
  int i = blockIdx.x * blockDim.x + threadIdx.x;
  const int stride = gridDim.x * blockDim.x;
  for (; i < TOT; i += stride) {
    int j = i;
    if (j < NX) {
      cast4(x, xb, j);
    } else if ((j -= NX) < NW1) {
      cast4(wq, wb, j);
    } else if ((j -= NW1) < NW2) {
      cast4(wk, wb + (size_t)NW1 * 4, j);
    } else if ((j -= NW2) < NW2) {
      cast4(wv, wb + (size_t)(NW1 + NW2) * 4, j);
    } else if ((j -= NW2) < NP) {
      cast4(wp, wpb, j);
    } else {
      j -= NP;  // rope table: entry (s, jj)
      const int s = j >> 5, jj = j & 31;
      const float inv = powf(10000.0f, -(float)jj * 0.03125f);
      const float ang = (float)s * inv;
      tab[j] = make_float2(cosf(ang), sinf(ang));
    }
  }
}

// ---------------- 2/5) B^T GEMM: 128^2, 3-buffer counted-vmcnt pipeline ------
// (R12 structure, measured equal-best: MfmaUtil ~29, conflicts 0.)
template <typename CT, bool FUSE>
__global__ __launch_bounds__(256) void gemm_bt(const __bf16* __restrict__ A,
                                               const __bf16* __restrict__ B,
                                               CT* __restrict__ C, int N, int K, int nbn,
                                               const float2* __restrict__ tab) {
  __shared__ __bf16 As[3][128 * 32];
  __shared__ __bf16 Bs[3][128 * 32];
  const int nwg = gridDim.x;
  const int id = blockIdx.x;
  const int xid = (id & 7) * (nwg >> 3) + (id >> 3);
  const int bm = xid / nbn;
  const int bn = xid - bm * nbn;
  const int t = threadIdx.x;
  const int l = t & 63, w = t >> 6;
  const int wr = w >> 1, wc = w & 1;
  const int lr = l & 15, lk = l >> 4;
  const __bf16* Ab = A + (size_t)bm * 128 * K;
  const __bf16* Bb = B + (size_t)bn * 128 * K;
  const int srow = t >> 2;                              // 0..63 (also +64)
  const int scol = ((t & 3) ^ ((srow >> 1) & 3)) << 3;  // inverse swizzle on src
  f32x4 acc[4][4] = {};

  auto stage = [&](int kt, int buf) {
    const int k0 = kt << 5;
    gload_lds16(Ab + (size_t)srow * K + k0 + scol, &As[buf][t * 8]);
    gload_lds16(Ab + (size_t)(srow + 64) * K + k0 + scol, &As[buf][2048 + t * 8]);
    gload_lds16(Bb + (size_t)srow * K + k0 + scol, &Bs[buf][t * 8]);
    gload_lds16(Bb + (size_t)(srow + 64) * K + k0 + scol, &Bs[buf][2048 + t * 8]);
  };

  stage(0, 0);
  stage(1, 1);
  asm volatile("s_waitcnt vmcnt(4)" ::: "memory");
  __builtin_amdgcn_s_barrier();

  const int NT = K >> 5;
  int cur = 0;
  for (int kt = 0; kt < NT; ++kt) {
    if (kt + 2 < NT) {
      int c2 = cur + 2;
      if (c2 >= 3) c2 -= 3;
      stage(kt + 2, c2);  // issue 2-ahead (async)
    }

    bf16x8 af[4], bfr[4];
#pragma unroll
    for (int m = 0; m < 4; ++m) {
      const int row = wr * 64 + m * 16 + lr;
      af[m] = *(const bf16x8*)&As[cur][row * 32 + ((lk ^ ((row >> 1) & 3)) << 3)];
    }
#pragma unroll
    for (int n = 0; n < 4; ++n) {
      const int row = wc * 64 + n * 16 + lr;
      bfr[n] = *(const bf16x8*)&Bs[cur][row * 32 + ((lk ^ ((row >> 1) & 3)) << 3)];
    }
#pragma unroll
    for (int m = 0; m < 4; ++m)
#pragma unroll
      for (int n = 0; n < 4; ++n) acc[m][n] = MFMA16x16x32(af[m], bfr[n], acc[m][n]);

    if (kt + 2 < NT)
      asm volatile("s_waitcnt vmcnt(4)" ::: "memory");
    else
      asm volatile("s_waitcnt vmcnt(0)" ::: "memory");
    __builtin_amdgcn_s_barrier();

    ++cur;
    if (cur == 3) cur = 0;
  }

  if constexpr (FUSE) {
    // bn 0..15 = q heads, 16..19 = k heads, 20..23 = v (plain store)
    if (bn < 20) {
      __syncthreads();  // full drain before LDS reuse
      __shared__ float Ls[2][128];
      float ssp[4][4];
#pragma unroll
      for (int m = 0; m < 4; ++m)
#pragma unroll
        for (int i = 0; i < 4; ++i) {
          float s = 0.0f;
#pragma unroll
          for (int n = 0; n < 4; ++n) s += acc[m][n][i] * acc[m][n][i];
#pragma unroll
          for (int off = 1; off < 16; off <<= 1) s += __shfl_xor(s, off);
          ssp[m][i] = s;
        }
      if (lr == 0) {
#pragma unroll
        for (int m = 0; m < 4; ++m)
#pragma unroll
          for (int i = 0; i < 4; ++i)
            Ls[wc][wr * 64 + m * 16 + lk * 4 + i] = ssp[m][i];
      }
      __syncthreads();
      const bool isq = (bn < 16);
      const float qs = isq ? 0.1275174457f : 1.0f;  // (1/sqrt(128))*log2(e)
#pragma unroll
      for (int m = 0; m < 4; ++m) {
#pragma unroll
        for (int i = 0; i < 4; ++i) {
          const int rl = wr * 64 + m * 16 + lk * 4 + i;
          const int rg = bm * 128 + rl;
          const float sc =
              rsqrtf((Ls[0][rl] + Ls[1][rl]) * (1.0f / 128.0f) +
                     1.1920928955078125e-07f) *
              qs;
          CT* Cr = C + (size_t)rg * N + bn * 128;
          if (wc == 0) {
            const int s = rg & 1023;
#pragma unroll
            for (int n = 0; n < 2; ++n) {
              const int j = n * 16 + lr;
              const float2 cs = tab[s * 32 + j];
              const float x1 = acc[m][n][i], x2 = acc[m][n + 2][i];
              Cr[j] = (CT)((x1 * cs.x + x2 * cs.y) * sc);
              Cr[j + 32] = (CT)((-x1 * cs.y + x2 * cs.x) * sc);
            }
          } else {
#pragma unroll
            for (int n = 0; n < 4; ++n)
              Cr[64 + n * 16 + lr] = (CT)(acc[m][n][i] * sc);
          }
        }
      }
      return;
    }
  }

#pragma unroll
  for (int m = 0; m < 4; ++m) {
    const int row0 = bm * 128 + wr * 64 + m * 16 + lk * 4;
#pragma unroll
    for (int n = 0; n < 4; ++n) {
      const int col = bn * 128 + wc * 64 + n * 16 + lr;
#pragma unroll
      for (int i = 0; i < 4; ++i) C[(size_t)(row0 + i) * N + col] = (CT)acc[m][n][i];
    }
  }
}

// ---------------- 3) V transpose: Vt[b,kvh][d][kv ^ ((d&7)<<3)] -------------
__global__ __launch_bounds__(256) void vtrans(const __bf16* __restrict__ qkv,
                                              __bf16* __restrict__ vt) {
  __shared__ __bf16 L[64 * 128];
  const int tile = blockIdx.x;  // (b*4+kvh)*16 + st
  const int st = tile & 15, bk = tile >> 4;
  const int b = bk >> 2, kvh = bk & 3;
  const int t = threadIdx.x;
  const int s0 = st * 64;
  const __bf16* src = qkv + ((size_t)(b * 1024 + s0)) * 3072 + 2560 + kvh * 128;
#pragma unroll
  for (int r = 0; r < 4; ++r) {
    const int off = r * 2048 + t * 8;
    const int s = off >> 7, d = off & 127;
    bf16x8 v = *(const bf16x8*)(src + (size_t)s * 3072 + d);
    *(bf16x8*)&L[s * 128 + (d ^ ((s & 7) << 3) ^ (((s >> 3) & 7) << 3))] = v;
  }
  __syncthreads();
  __bf16* dst = vt + (size_t)bk * 128 * 1024;
#pragma unroll
  for (int r = 0; r < 4; ++r) {
    const int off = r * 2048 + t * 8;
    const int d = off >> 6, sc = off & 63;
    bf16x8 v;
#pragma unroll
    for (int j = 0; j < 8; ++j) {
      const int s = sc + j;
      v[j] = L[s * 128 + (d ^ ((s & 7) << 3) ^ (((s >> 3) & 7) << 3))];
    }
    *(bf16x8*)&dst[(size_t)d * 1024 + ((s0 + sc) ^ ((d & 7) << 3))] = v;
  }
}

// ---------------- 4) causal flash attention + v-projection correction ------
// KVBLK=128 SEQUENTIAL-PAIR: 256 blocks (=1/CU) x 512 threads (8 waves).
// Each block: one (b,h), passes q-tiles (7-pr) then (pr); pass qt needs
// qt+1 kv-iterations of 128 -> total (8-pr)+(pr+1) = 9 per block, exactly
// balanced. Every wave active in every tile (no divergent skip); mask only
// at tt==qt. LDS 160 KB: Ks[2][128x128] + Vs[2][128x128] + Ps[8][16x128].
// XCD grouping: blocks of one (b,kvh) group share an XCD (id&7).
__global__ __launch_bounds__(512) void attn_fwd(const __bf16* __restrict__ qkv,
                                                const __bf16* __restrict__ vt,
                                                __bf16* __restrict__ y) {
  const int id = blockIdx.x;
  const int g = (id & 7) | (((id >> 3) & 1) << 3);  // (b,kvh) group 0..15
  const int b = g >> 2, kvh = g & 3;
  const int hi = (id >> 4) & 3;
  const int pr = (id >> 6) & 3;
  const int h = kvh * 4 + hi;

  const int t = threadIdx.x;
  const int l = t & 63, w = t >> 6;  // 8 waves
  const int lr = l & 15, lk = l >> 4;
  const int lr8 = lr & 7;

  __shared__ __bf16 Ks[2][128 * 128];
  __shared__ __bf16 Vs[2][128 * 128];
  __shared__ __bf16 Ps[8][16 * 128];

  const size_t rb = (size_t)b * 1024;
  const __bf16* Kg0 = qkv + rb * 3072 + 2048 + kvh * 128;
  const __bf16* Vtb = vt + (size_t)(b * 4 + kvh) * 128 * 1024;

  // staging: 4 rounds each for K (128x128) and V^T (128x128); round r:
  // dest off = r*4096 + t*8 -> row/d = r*32 + (t>>4), colgrp = t&15.
  const int srow = t >> 4;  // 0..31
  const int scg = t & 15;
  const int kcolg = (scg ^ (srow & 7)) << 3;  // inverse swizzle on K source

  auto stageK = [&](int kv0, int buf) {
#pragma unroll
    for (int r = 0; r < 4; ++r)
      gload_lds16(Kg0 + (size_t)(kv0 + r * 32 + srow) * 3072 + kcolg,
                  &Ks[buf][0] + r * 4096 + t * 8);
  };
  auto stageV = [&](int kv0, int buf) {
#pragma unroll
    for (int r = 0; r < 4; ++r)
      gload_lds16(Vtb + (size_t)(r * 32 + srow) * 1024 + kv0 + scg * 8,
                  &Vs[buf][0] + r * 4096 + t * 8);
  };

#pragma unroll 1
  for (int pass = 0; pass < 2; ++pass) {
    const int qt = pass ? pr : (7 - pr);  // heavy pass first
    const int q0 = qt << 7;
    const int nt = qt + 1;

    // Q fragments -> registers; wave w owns q-rows q0 + w*16 .. +15
    bf16x8 aq[4];
    {
      const __bf16* qrow = qkv + (rb + q0 + w * 16 + lr) * 3072 + h * 128 + lk * 8;
#pragma unroll
      for (int kk = 0; kk < 4; ++kk) aq[kk] = *(const bf16x8*)(qrow + kk * 32);
    }

    float m_i[4], l_i[4];
    f32x4 o[8] = {};
#pragma unroll
    for (int i = 0; i < 4; ++i) {
      m_i[i] = -1e30f;
      l_i[i] = 0.0f;
    }

    const int rowg0 = q0 + w * 16 + lk * 4;

    // prologue: stage tile 0 into buf 0 (prior pass's LDS reads completed
    // before its final barrier)
    stageK(0, 0);
    stageV(0, 0);
    __syncthreads();  // drains vmcnt -> buf0 ready

    for (int tt = 0; tt < nt; ++tt) {
      const int kv0 = tt << 7;
      const int cur = tt & 1;
      // issue next tile's staging first (async; lands in other buffer)
      if (tt + 1 < nt) {
        stageK(kv0 + 128, cur ^ 1);
        stageV(kv0 + 128, cur ^ 1);
      }

      // S = Q K^T (log2-domain: q pre-scaled in gemm epilogue)
      f32x4 sacc[8] = {};
      __builtin_amdgcn_s_setprio(1);
#pragma unroll
      for (int kk = 0; kk < 4; ++kk) {
#pragma unroll
        for (int n = 0; n < 8; ++n) {
          const bf16x8 bk = *(const bf16x8*)&Ks[cur][(n * 16 + lr) * 128 +
                                                    ((kk * 32 + lk * 8) ^ (lr8 << 3))];
          sacc[n] = MFMA16x16x32(aq[kk], bk, sacc[n]);
        }
      }
      __builtin_amdgcn_s_setprio(0);

      // causal mask (diagonal tile only) + online softmax (exp2)
      float pm[4];
#pragma unroll
      for (int i = 0; i < 4; ++i) pm[i] = -1e30f;
      if (tt == qt) {  // diagonal tile: mask needed
#pragma unroll
        for (int n = 0; n < 8; ++n) {
          const int colg = kv0 + n * 16 + lr;
#pragma unroll
          for (int i = 0; i < 4; ++i) {
            if (colg > rowg0 + i) sacc[n][i] = -1e30f;
            pm[i] = fmaxf(pm[i], sacc[n][i]);
          }
        }
      } else {
#pragma unroll
        for (int n = 0; n < 8; ++n)
#pragma unroll
          for (int i = 0; i < 4; ++i) pm[i] = fmaxf(pm[i], sacc[n][i]);
      }
#pragma unroll
      for (int i = 0; i < 4; ++i) {
        pm[i] = fmaxf(pm[i], __shfl_xor(pm[i], 1));
        pm[i] = fmaxf(pm[i], __shfl_xor(pm[i], 2));
        pm[i] = fmaxf(pm[i], __shfl_xor(pm[i], 4));
        pm[i] = fmaxf(pm[i], __shfl_xor(pm[i], 8));
      }
      float alpha[4], rs[4];
#pragma unroll
      for (int i = 0; i < 4; ++i) {
        const float mn = fmaxf(m_i[i], pm[i]);
        alpha[i] = EXP2(m_i[i] - mn);
        m_i[i] = mn;
        rs[i] = 0.0f;
      }
#pragma unroll
      for (int n = 0; n < 8; ++n) {
#pragma unroll
        for (int i = 0; i < 4; ++i) {
          const float p = EXP2(sacc[n][i] - m_i[i]);
          rs[i] += p;
          const int prow = lk * 4 + i;
          Ps[w][prow * 128 + ((n * 16 + lr) ^ ((prow & 7) << 3))] = (__bf16)p;
        }
      }
#pragma unroll
      for (int i = 0; i < 4; ++i) {
        rs[i] += __shfl_xor(rs[i], 1);
        rs[i] += __shfl_xor(rs[i], 2);
        rs[i] += __shfl_xor(rs[i], 4);
        rs[i] += __shfl_xor(rs[i], 8);
        l_i[i] = l_i[i] * alpha[i] + rs[i];
      }
#pragma unroll
      for (int f = 0; f < 8; ++f)
#pragma unroll
        for (int i = 0; i < 4; ++i) o[f][i] *= alpha[i];

      // O += P V  (4 k-slices of 32 over the 128 kv columns)
      __builtin_amdgcn_s_setprio(1);
#pragma unroll
      for (int ks = 0; ks < 4; ++ks) {
        const bf16x8 pa =
            *(const bf16x8*)&Ps[w][lr * 128 + ((ks * 32 + lk * 8) ^ (lr8 << 3))];
#pragma unroll
        for (int f = 0; f < 8; ++f) {
          const bf16x8 vb = *(const bf16x8*)&Vs[cur][(f * 16 + lr) * 128 +
                                                     ((ks * 32 + lk * 8) ^ (lr8 << 3))];
          o[f] = MFMA16x16x32(pa, vb, o[f]);
        }
      }
      __builtin_amdgcn_s_setprio(0);

      __syncthreads();  // next tile staged (vmcnt drained) + all LDS reads done
    }

    // epilogue: normalize, v-projection correction, store bf16
#pragma unroll
    for (int i = 0; i < 4; ++i) {
      const int sg = rowg0 + i;
      const size_t mg = rb + sg;
      const __bf16* vp = qkv + mg * 3072 + 2560 + kvh * 128;
      const float invl = 1.0f / l_i[i];
      float vvv[8], yvv[8];
      float dyv = 0.0f, dvv = 0.0f;
#pragma unroll
      for (int f = 0; f < 8; ++f) {
        const float vf = (float)vp[f * 16 + lr];
        const float yf = o[f][i] * invl;
        vvv[f] = vf;
        yvv[f] = yf;
        dyv += yf * vf;
        dvv += vf * vf;
      }
#pragma unroll
      for (int off = 1; off < 16; off <<= 1) {
        dyv += __shfl_xor(dyv, off);
        dvv += __shfl_xor(dvv, off);
      }
      const float proj = dyv / fmaxf(dvv, 1e-6f);
      __bf16* yp = y + mg * 2048 + h * 128;
#pragma unroll
      for (int f = 0; f < 8; ++f) yp[f * 16 + lr] = (__bf16)(yvv[f] - proj * vvv[f]);
    }
  }
}

// ---------------------------------------------------------------------------
extern "C" void kernel_launch(void* const* d_in, const int* in_sizes, int n_in,
                              void* d_out, int out_size, void* d_ws, size_t ws_size,
                              hipStream_t stream) {
  const float* x = (const float*)d_in[0];
  const float* Wq = (const float*)d_in[2];
  const float* Wk = (const float*)d_in[3];
  const float* Wv = (const float*)d_in[4];
  const float* Wp = (const float*)d_in[5];
  float* out = (float*)d_out;

  __bf16* xb = (__bf16*)d_ws;                // 4096x2048
  __bf16* Wb = xb + (size_t)4096 * 2048;     // 3072x2048  [Wq;Wk;Wv]
  __bf16* Wpb = Wb + (size_t)3072 * 2048;    // 2048x2048
  __bf16* qkv = Wpb + (size_t)2048 * 2048;   // 4096x3072
  __bf16* yb = qkv + (size_t)4096 * 3072;    // 4096x2048
  float2* tab = (float2*)(yb + (size_t)4096 * 2048);  // 1024x32 cos/sin
  __bf16* vt = xb;  // reuse xb region after qkv GEMM (4*4*128*1024 elems)

  prep<<<2048, 256, 0, stream>>>(x, Wq, Wk, Wv, Wp, xb, Wb, Wpb, tab);

  gemm_bt<__bf16, true><<<768, 256, 0, stream>>>(xb, Wb, qkv, 3072, 2048, 24, tab);
  vtrans<<<256, 256, 0, stream>>>(qkv, vt);
  attn_fwd<<<256, 512, 0, stream>>>(qkv, vt, yb);
  gemm_bt<float, false><<<512, 256, 0, stream>>>(yb, Wpb, out, 2048, 2048, 16, nullptr);
}

// Round 15
// 176.380 us; speedup vs baseline: 1.1147x; 1.0133x over previous
//
#include <hip/hip_runtime.h>

// ---------------------------------------------------------------------------
// SelfAttention fused pipeline for MI355X (gfx950)
// B=4 S=1024 DIM=2048 H=16 KV=4 HD=128 ROPE_DIM=64
//
// Stages (all on `stream`), 5 launches:
//  1) prep: casts fp32->bf16 (x | Wq|Wk|Wv | Wproj) + rope cos/sin table
//  2) gemm_bt<FUSE>: qkv = xb @ Wcat^T (128^2, 3-buffer counted-vmcnt,
//     swizzled LDS) + fused RMSNorm/RoPE/log2-prescale epilogue
//  3) vtrans: V -> Vt_global[b,kvh][d][kv] (pre-swizzled for LDS staging)
//  4) attn_fwd: causal flash attention + v-proj correction -> y bf16
//     KVBLK=128 sequential-pair (9 iters/block, balanced, 160 KB LDS)
//     + ones-MFMA row-sum softmax denom + defer-max rescale (T13)
//  5) gemm_bt: out = y @ Wproj^T (fp32 out)
// ---------------------------------------------------------------------------

typedef __attribute__((ext_vector_type(8))) __bf16 bf16x8;
typedef __attribute__((ext_vector_type(4))) __bf16 bf16x4;
typedef __attribute__((ext_vector_type(4))) float f32x4;

static_assert(sizeof(__bf16) == 2, "bf16 size");

#define MFMA16x16x32(a, b, c) __builtin_amdgcn_mfma_f32_16x16x32_bf16((a), (b), (c), 0, 0, 0)

#if __has_builtin(__builtin_amdgcn_exp2f)
#define EXP2(x) __builtin_amdgcn_exp2f(x)
#else
#define EXP2(x) exp2f(x)
#endif

__device__ __forceinline__ void gload_lds16(const void* g, void* l) {
  __builtin_amdgcn_global_load_lds((const __attribute__((address_space(1))) void*)g,
                                   (__attribute__((address_space(3))) void*)l, 16, 0, 0);
}

// ---------------- 1) prep: all casts + rope table, one kernel ----------------
__global__ __launch_bounds__(256) void prep(const float* __restrict__ x,
                                            const float* __restrict__ wq,
                                            const float* __restrict__ wk,
                                            const float* __restrict__ wv,
                                            const float* __restrict__ wp,
                                            __bf16* __restrict__ xb,
                                            __bf16* __restrict__ wb,
                                            __bf16* __restrict__ wpb,
                                            float2* __restrict__ tab) {
  constexpr int NX = 2097152;   // 4096*2048/4
  constexpr int NW1 = 1048576;  // 2048*2048/4
  constexpr int NW2 = 262144;   // 512*2048/4
  constexpr int NP = 1048576;   // 2048*2048/4
  constexpr int NT = 32768;     // 1024*32 rope table entries
  constexpr int TOT = NX + NW1 + 2 * NW2 + NP + NT;
  auto cast4 = [](const float* s, __bf16* d, int i) {
    f32x4 v = ((const f32x4*)s)[i];
    bf16x4 o;
    o[0] = (__bf16)v[0];
    o[1] = (__bf16)v[1];
    o[2] = (__bf16)v[2];
    o[3] = (__bf16)v[3];
    ((bf16x4*)d)[i] = o;
  };
  int i = blockIdx.x * blockDim.x + threadIdx.x;
  const int stride = gridDim.x * blockDim.x;
  for (; i < TOT; i += stride) {
    int j = i;
    if (j < NX) {
      cast4(x, xb, j);
    } else if ((j -= NX) < NW1) {
      cast4(wq, wb, j);
    } else if ((j -= NW1) < NW2) {
      cast4(wk, wb + (size_t)NW1 * 4, j);
    } else if ((j -= NW2) < NW2) {
      cast4(wv, wb + (size_t)(NW1 + NW2) * 4, j);
    } else if ((j -= NW2) < NP) {
      cast4(wp, wpb, j);
    } else {
      j -= NP;  // rope table: entry (s, jj)
      const int s = j >> 5, jj = j & 31;
      const float inv = powf(10000.0f, -(float)jj * 0.03125f);
      const float ang = (float)s * inv;
      tab[j] = make_float2(cosf(ang), sinf(ang));
    }
  }
}

// ---------------- 2/5) B^T GEMM: 128^2, 3-buffer counted-vmcnt pipeline ------
// (R12 structure, measured equal-best: MfmaUtil ~29, conflicts 0.)
template <typename CT, bool FUSE>
__global__ __launch_bounds__(256) void gemm_bt(const __bf16* __restrict__ A,
                                               const __bf16* __restrict__ B,
                                               CT* __restrict__ C, int N, int K, int nbn,
                                               const float2* __restrict__ tab) {
  __shared__ __bf16 As[3][128 * 32];
  __shared__ __bf16 Bs[3][128 * 32];
  const int nwg = gridDim.x;
  const int id = blockIdx.x;
  const int xid = (id & 7) * (nwg >> 3) + (id >> 3);
  const int bm = xid / nbn;
  const int bn = xid - bm * nbn;
  const int t = threadIdx.x;
  const int l = t & 63, w = t >> 6;
  const int wr = w >> 1, wc = w & 1;
  const int lr = l & 15, lk = l >> 4;
  const __bf16* Ab = A + (size_t)bm * 128 * K;
  const __bf16* Bb = B + (size_t)bn * 128 * K;
  const int srow = t >> 2;                              // 0..63 (also +64)
  const int scol = ((t & 3) ^ ((srow >> 1) & 3)) << 3;  // inverse swizzle on src
  f32x4 acc[4][4] = {};

  auto stage = [&](int kt, int buf) {
    const int k0 = kt << 5;
    gload_lds16(Ab + (size_t)srow * K + k0 + scol, &As[buf][t * 8]);
    gload_lds16(Ab + (size_t)(srow + 64) * K + k0 + scol, &As[buf][2048 + t * 8]);
    gload_lds16(Bb + (size_t)srow * K + k0 + scol, &Bs[buf][t * 8]);
    gload_lds16(Bb + (size_t)(srow + 64) * K + k0 + scol, &Bs[buf][2048 + t * 8]);
  };

  stage(0, 0);
  stage(1, 1);
  asm volatile("s_waitcnt vmcnt(4)" ::: "memory");
  __builtin_amdgcn_s_barrier();

  const int NT = K >> 5;
  int cur = 0;
  for (int kt = 0; kt < NT; ++kt) {
    if (kt + 2 < NT) {
      int c2 = cur + 2;
      if (c2 >= 3) c2 -= 3;
      stage(kt + 2, c2);  // issue 2-ahead (async)
    }

    bf16x8 af[4], bfr[4];
#pragma unroll
    for (int m = 0; m < 4; ++m) {
      const int row = wr * 64 + m * 16 + lr;
      af[m] = *(const bf16x8*)&As[cur][row * 32 + ((lk ^ ((row >> 1) & 3)) << 3)];
    }
#pragma unroll
    for (int n = 0; n < 4; ++n) {
      const int row = wc * 64 + n * 16 + lr;
      bfr[n] = *(const bf16x8*)&Bs[cur][row * 32 + ((lk ^ ((row >> 1) & 3)) << 3)];
    }
#pragma unroll
    for (int m = 0; m < 4; ++m)
#pragma unroll
      for (int n = 0; n < 4; ++n) acc[m][n] = MFMA16x16x32(af[m], bfr[n], acc[m][n]);

    if (kt + 2 < NT)
      asm volatile("s_waitcnt vmcnt(4)" ::: "memory");
    else
      asm volatile("s_waitcnt vmcnt(0)" ::: "memory");
    __builtin_amdgcn_s_barrier();

    ++cur;
    if (cur == 3) cur = 0;
  }

  if constexpr (FUSE) {
    // bn 0..15 = q heads, 16..19 = k heads, 20..23 = v (plain store)
    if (bn < 20) {
      __syncthreads();  // full drain before LDS reuse
      __shared__ float Ls[2][128];
      float ssp[4][4];
#pragma unroll
      for (int m = 0; m < 4; ++m)
#pragma unroll
        for (int i = 0; i < 4; ++i) {
          float s = 0.0f;
#pragma unroll
          for (int n = 0; n < 4; ++n) s += acc[m][n][i] * acc[m][n][i];
#pragma unroll
          for (int off = 1; off < 16; off <<= 1) s += __shfl_xor(s, off);
          ssp[m][i] = s;
        }
      if (lr == 0) {
#pragma unroll
        for (int m = 0; m < 4; ++m)
#pragma unroll
          for (int i = 0; i < 4; ++i)
            Ls[wc][wr * 64 + m * 16 + lk * 4 + i] = ssp[m][i];
      }
      __syncthreads();
      const bool isq = (bn < 16);
      const float qs = isq ? 0.1275174457f : 1.0f;  // (1/sqrt(128))*log2(e)
#pragma unroll
      for (int m = 0; m < 4; ++m) {
#pragma unroll
        for (int i = 0; i < 4; ++i) {
          const int rl = wr * 64 + m * 16 + lk * 4 + i;
          const int rg = bm * 128 + rl;
          const float sc =
              rsqrtf((Ls[0][rl] + Ls[1][rl]) * (1.0f / 128.0f) +
                     1.1920928955078125e-07f) *
              qs;
          CT* Cr = C + (size_t)rg * N + bn * 128;
          if (wc == 0) {
            const int s = rg & 1023;
#pragma unroll
            for (int n = 0; n < 2; ++n) {
              const int j = n * 16 + lr;
              const float2 cs = tab[s * 32 + j];
              const float x1 = acc[m][n][i], x2 = acc[m][n + 2][i];
              Cr[j] = (CT)((x1 * cs.x + x2 * cs.y) * sc);
              Cr[j + 32] = (CT)((-x1 * cs.y + x2 * cs.x) * sc);
            }
          } else {
#pragma unroll
            for (int n = 0; n < 4; ++n)
              Cr[64 + n * 16 + lr] = (CT)(acc[m][n][i] * sc);
          }
        }
      }
      return;
    }
  }

#pragma unroll
  for (int m = 0; m < 4; ++m) {
    const int row0 = bm * 128 + wr * 64 + m * 16 + lk * 4;
#pragma unroll
    for (int n = 0; n < 4; ++n) {
      const int col = bn * 128 + wc * 64 + n * 16 + lr;
#pragma unroll
      for (int i = 0; i < 4; ++i) C[(size_t)(row0 + i) * N + col] = (CT)acc[m][n][i];
    }
  }
}

// ---------------- 3) V transpose: Vt[b,kvh][d][kv ^ ((d&7)<<3)] -------------
__global__ __launch_bounds__(256) void vtrans(const __bf16* __restrict__ qkv,
                                              __bf16* __restrict__ vt) {
  __shared__ __bf16 L[64 * 128];
  const int tile = blockIdx.x;  // (b*4+kvh)*16 + st
  const int st = tile & 15, bk = tile >> 4;
  const int b = bk >> 2, kvh = bk & 3;
  const int t = threadIdx.x;
  const int s0 = st * 64;
  const __bf16* src = qkv + ((size_t)(b * 1024 + s0)) * 3072 + 2560 + kvh * 128;
#pragma unroll
  for (int r = 0; r < 4; ++r) {
    const int off = r * 2048 + t * 8;
    const int s = off >> 7, d = off & 127;
    bf16x8 v = *(const bf16x8*)(src + (size_t)s * 3072 + d);
    *(bf16x8*)&L[s * 128 + (d ^ ((s & 7) << 3) ^ (((s >> 3) & 7) << 3))] = v;
  }
  __syncthreads();
  __bf16* dst = vt + (size_t)bk * 128 * 1024;
#pragma unroll
  for (int r = 0; r < 4; ++r) {
    const int off = r * 2048 + t * 8;
    const int d = off >> 6, sc = off & 63;
    bf16x8 v;
#pragma unroll
    for (int j = 0; j < 8; ++j) {
      const int s = sc + j;
      v[j] = L[s * 128 + (d ^ ((s & 7) << 3) ^ (((s >> 3) & 7) << 3))];
    }
    *(bf16x8*)&dst[(size_t)d * 1024 + ((s0 + sc) ^ ((d & 7) << 3))] = v;
  }
}

// ---------------- 4) causal flash attention + v-projection correction ------
// KVBLK=128 SEQUENTIAL-PAIR (R14) + ones-MFMA row-sum denom + defer-max:
// 256 blocks (=1/CU) x 512 threads (8 waves); passes (7-pr, pr) => exactly
// 9 kv-iterations/block. Softmax denominator computed as MFMA(P, ones)
// row-sum (B=ones => C[r][c]=rowsum(A[r]), already in each lane's rows --
// no cross-lane traffic). O/l rescale skipped unless the running max grew
// by >8 (log2 domain; P bounded by 2^8, safe in bf16/fp32).
__global__ __launch_bounds__(512) void attn_fwd(const __bf16* __restrict__ qkv,
                                                const __bf16* __restrict__ vt,
                                                __bf16* __restrict__ y) {
  const int id = blockIdx.x;
  const int g = (id & 7) | (((id >> 3) & 1) << 3);  // (b,kvh) group 0..15
  const int b = g >> 2, kvh = g & 3;
  const int hi = (id >> 4) & 3;
  const int pr = (id >> 6) & 3;
  const int h = kvh * 4 + hi;

  const int t = threadIdx.x;
  const int l = t & 63, w = t >> 6;  // 8 waves
  const int lr = l & 15, lk = l >> 4;
  const int lr8 = lr & 7;

  __shared__ __bf16 Ks[2][128 * 128];
  __shared__ __bf16 Vs[2][128 * 128];
  __shared__ __bf16 Ps[8][16 * 128];

  const size_t rb = (size_t)b * 1024;
  const __bf16* Kg0 = qkv + rb * 3072 + 2048 + kvh * 128;
  const __bf16* Vtb = vt + (size_t)(b * 4 + kvh) * 128 * 1024;

  const int srow = t >> 4;  // 0..31
  const int scg = t & 15;
  const int kcolg = (scg ^ (srow & 7)) << 3;  // inverse swizzle on K source

  auto stageK = [&](int kv0, int buf) {
#pragma unroll
    for (int r = 0; r < 4; ++r)
      gload_lds16(Kg0 + (size_t)(kv0 + r * 32 + srow) * 3072 + kcolg,
                  &Ks[buf][0] + r * 4096 + t * 8);
  };
  auto stageV = [&](int kv0, int buf) {
#pragma unroll
    for (int r = 0; r < 4; ++r)
      gload_lds16(Vtb + (size_t)(r * 32 + srow) * 1024 + kv0 + scg * 8,
                  &Vs[buf][0] + r * 4096 + t * 8);
  };

  bf16x8 onesb;
#pragma unroll
  for (int j = 0; j < 8; ++j) onesb[j] = (__bf16)1.0f;

#pragma unroll 1
  for (int pass = 0; pass < 2; ++pass) {
    const int qt = pass ? pr : (7 - pr);  // heavy pass first
    const int q0 = qt << 7;
    const int nt = qt + 1;

    // Q fragments -> registers; wave w owns q-rows q0 + w*16 .. +15
    bf16x8 aq[4];
    {
      const __bf16* qrow = qkv + (rb + q0 + w * 16 + lr) * 3072 + h * 128 + lk * 8;
#pragma unroll
      for (int kk = 0; kk < 4; ++kk) aq[kk] = *(const bf16x8*)(qrow + kk * 32);
    }

    float m_i[4], l_i[4];
    f32x4 o[8] = {};
#pragma unroll
    for (int i = 0; i < 4; ++i) {
      m_i[i] = -1e30f;
      l_i[i] = 0.0f;
    }

    const int rowg0 = q0 + w * 16 + lk * 4;

    // prologue: stage tile 0 into buf 0
    stageK(0, 0);
    stageV(0, 0);
    __syncthreads();  // drains vmcnt -> buf0 ready

    for (int tt = 0; tt < nt; ++tt) {
      const int kv0 = tt << 7;
      const int cur = tt & 1;
      if (tt + 1 < nt) {
        stageK(kv0 + 128, cur ^ 1);
        stageV(kv0 + 128, cur ^ 1);
      }

      // S = Q K^T (log2-domain: q pre-scaled in gemm epilogue)
      f32x4 sacc[8] = {};
      __builtin_amdgcn_s_setprio(1);
#pragma unroll
      for (int kk = 0; kk < 4; ++kk) {
#pragma unroll
        for (int n = 0; n < 8; ++n) {
          const bf16x8 bk = *(const bf16x8*)&Ks[cur][(n * 16 + lr) * 128 +
                                                    ((kk * 32 + lk * 8) ^ (lr8 << 3))];
          sacc[n] = MFMA16x16x32(aq[kk], bk, sacc[n]);
        }
      }
      __builtin_amdgcn_s_setprio(0);

      // causal mask (diagonal tile only) + tile row-max
      float pm[4];
#pragma unroll
      for (int i = 0; i < 4; ++i) pm[i] = -1e30f;
      if (tt == qt) {  // diagonal tile: mask needed
#pragma unroll
        for (int n = 0; n < 8; ++n) {
          const int colg = kv0 + n * 16 + lr;
#pragma unroll
          for (int i = 0; i < 4; ++i) {
            if (colg > rowg0 + i) sacc[n][i] = -1e30f;
            pm[i] = fmaxf(pm[i], sacc[n][i]);
          }
        }
      } else {
#pragma unroll
        for (int n = 0; n < 8; ++n)
#pragma unroll
          for (int i = 0; i < 4; ++i) pm[i] = fmaxf(pm[i], sacc[n][i]);
      }
#pragma unroll
      for (int i = 0; i < 4; ++i) {
        pm[i] = fmaxf(pm[i], __shfl_xor(pm[i], 1));
        pm[i] = fmaxf(pm[i], __shfl_xor(pm[i], 2));
        pm[i] = fmaxf(pm[i], __shfl_xor(pm[i], 4));
        pm[i] = fmaxf(pm[i], __shfl_xor(pm[i], 8));
      }

      // defer-max: rescale only when the running max grew by >8 (log2)
      const float dm = fmaxf(fmaxf(pm[0] - m_i[0], pm[1] - m_i[1]),
                             fmaxf(pm[2] - m_i[2], pm[3] - m_i[3]));
      if (__any(dm > 8.0f)) {
#pragma unroll
        for (int i = 0; i < 4; ++i) {
          const float mn = fmaxf(m_i[i], pm[i]);
          const float al = EXP2(m_i[i] - mn);
          m_i[i] = mn;
          l_i[i] *= al;
#pragma unroll
          for (int f = 0; f < 8; ++f) o[f][i] *= al;
        }
      }

      // P = exp2(S - m) -> Ps (bf16, swizzled)
#pragma unroll
      for (int n = 0; n < 8; ++n) {
#pragma unroll
        for (int i = 0; i < 4; ++i) {
          const float p = EXP2(sacc[n][i] - m_i[i]);
          const int prow = lk * 4 + i;
          Ps[w][prow * 128 + ((n * 16 + lr) ^ ((prow & 7) << 3))] = (__bf16)p;
        }
      }

      // O += P V ; l += P·1 (ones-MFMA row-sum, no shuffles)
      f32x4 lsum = {};
      __builtin_amdgcn_s_setprio(1);
#pragma unroll
      for (int ks = 0; ks < 4; ++ks) {
        const bf16x8 pa =
            *(const bf16x8*)&Ps[w][lr * 128 + ((ks * 32 + lk * 8) ^ (lr8 << 3))];
        lsum = MFMA16x16x32(pa, onesb, lsum);
#pragma unroll
        for (int f = 0; f < 8; ++f) {
          const bf16x8 vb = *(const bf16x8*)&Vs[cur][(f * 16 + lr) * 128 +
                                                     ((ks * 32 + lk * 8) ^ (lr8 << 3))];
          o[f] = MFMA16x16x32(pa, vb, o[f]);
        }
      }
      __builtin_amdgcn_s_setprio(0);
#pragma unroll
      for (int i = 0; i < 4; ++i) l_i[i] += lsum[i];

      __syncthreads();  // next tile staged (vmcnt drained) + all LDS reads done
    }

    // epilogue: normalize, v-projection correction, store bf16
#pragma unroll
    for (int i = 0; i < 4; ++i) {
      const int sg = rowg0 + i;
      const size_t mg = rb + sg;
      const __bf16* vp = qkv + mg * 3072 + 2560 + kvh * 128;
      const float invl = 1.0f / l_i[i];
      float vvv[8], yvv[8];
      float dyv = 0.0f, dvv = 0.0f;
#pragma unroll
      for (int f = 0; f < 8; ++f) {
        const float vf = (float)vp[f * 16 + lr];
        const float yf = o[f][i] * invl;
        vvv[f] = vf;
        yvv[f] = yf;
        dyv += yf * vf;
        dvv += vf * vf;
      }
#pragma unroll
      for (int off = 1; off < 16; off <<= 1) {
        dyv += __shfl_xor(dyv, off);
        dvv += __shfl_xor(dvv, off);
      }
      const float proj = dyv / fmaxf(dvv, 1e-6f);
      __bf16* yp = y + mg * 2048 + h * 128;
#pragma unroll
      for (int f = 0; f < 8; ++f) yp[f * 16 + lr] = (__bf16)(yvv[f] - proj * vvv[f]);
    }
  }
}

// ---------------------------------------------------------------------------
extern "C" void kernel_launch(void* const* d_in, const int* in_sizes, int n_in,
                              void* d_out, int out_size, void* d_ws, size_t ws_size,
                              hipStream_t stream) {
  const float* x = (const float*)d_in[0];
  const float* Wq = (const float*)d_in[2];
  const float* Wk = (const float*)d_in[3];
  const float* Wv = (const float*)d_in[4];
  const float* Wp = (const float*)d_in[5];
  float* out = (float*)d_out;

  __bf16* xb = (__bf16*)d_ws;                // 4096x2048
  __bf16* Wb = xb + (size_t)4096 * 2048;     // 3072x2048  [Wq;Wk;Wv]
  __bf16* Wpb = Wb + (size_t)3072 * 2048;    // 2048x2048
  __bf16* qkv = Wpb + (size_t)2048 * 2048;   // 4096x3072
  __bf16* yb = qkv + (size_t)4096 * 3072;    // 4096x2048
  float2* tab = (float2*)(yb + (size_t)4096 * 2048);  // 1024x32 cos/sin
  __bf16* vt = xb;  // reuse xb region after qkv GEMM (4*4*128*1024 elems)

  prep<<<2048, 256, 0, stream>>>(x, Wq, Wk, Wv, Wp, xb, Wb, Wpb, tab);

  gemm_bt<__bf16, true><<<768, 256, 0, stream>>>(xb, Wb, qkv, 3072, 2048, 24, tab);
  vtrans<<<256, 256, 0, stream>>>(qkv, vt);
  attn_fwd<<<256, 512, 0, stream>>>(qkv, vt, yb);
  gemm_bt<float, false><<<512, 256, 0, stream>>>(yb, Wpb, out, 2048, 2048, 16, nullptr);
}

// Round 16
// 172.720 us; speedup vs baseline: 1.1383x; 1.0212x over previous
//
#include <hip/hip_runtime.h>

// ---------------------------------------------------------------------------
// SelfAttention fused pipeline for MI355X (gfx950)
// B=4 S=1024 DIM=2048 H=16 KV=4 HD=128 ROPE_DIM=64
//
// Stages (all on `stream`), 4 launches:
//  1) prep: casts fp32->bf16 (x | Wq|Wk|Wv | Wproj) + rope cos/sin table
//  2) gemm_bt<FUSE>: qkv = xb @ Wcat^T (128^2, 3-buffer counted-vmcnt,
//     swizzled LDS) + fused RMSNorm/RoPE/log2-prescale epilogue (q,k) and
//     fused V-transpose -> vt (pre-swizzled for attn LDS staging) (v)
//  3) attn_fwd: causal flash attention + v-proj correction -> y bf16
//     (KVBLK=128 sequential-pair, ones-MFMA denom, defer-max)
//  4) gemm_bt: out = y @ Wproj^T (fp32 out)
// ---------------------------------------------------------------------------

typedef __attribute__((ext_vector_type(8))) __bf16 bf16x8;
typedef __attribute__((ext_vector_type(4))) __bf16 bf16x4;
typedef __attribute__((ext_vector_type(4))) float f32x4;

static_assert(sizeof(__bf16) == 2, "bf16 size");

#define MFMA16x16x32(a, b, c) __builtin_amdgcn_mfma_f32_16x16x32_bf16((a), (b), (c), 0, 0, 0)

#if __has_builtin(__builtin_amdgcn_exp2f)
#define EXP2(x) __builtin_amdgcn_exp2f(x)
#else
#define EXP2(x) exp2f(x)
#endif

__device__ __forceinline__ void gload_lds16(const void* g, void* l) {
  __builtin_amdgcn_global_load_lds((const __attribute__((address_space(1))) void*)g,
                                   (__attribute__((address_space(3))) void*)l, 16, 0, 0);
}

// ---------------- 1) prep: all casts + rope table, one kernel ----------------
__global__ __launch_bounds__(256) void prep(const float* __restrict__ x,
                                            const float* __restrict__ wq,
                                            const float* __restrict__ wk,
                                            const float* __restrict__ wv,
                                            const float* __restrict__ wp,
                                            __bf16* __restrict__ xb,
                                            __bf16* __restrict__ wb,
                                            __bf16* __restrict__ wpb,
                                            float2* __restrict__ tab) {
  constexpr int NX = 2097152;   // 4096*2048/4
  constexpr int NW1 = 1048576;  // 2048*2048/4
  constexpr int NW2 = 262144;   // 512*2048/4
  constexpr int NP = 1048576;   // 2048*2048/4
  constexpr int NT = 32768;     // 1024*32 rope table entries
  constexpr int TOT = NX + NW1 + 2 * NW2 + NP + NT;
  auto cast4 = [](const float* s, __bf16* d, int i) {
    f32x4 v = ((const f32x4*)s)[i];
    bf16x4 o;
    o[0] = (__bf16)v[0];
    o[1] = (__bf16)v[1];
    o[2] = (__bf16)v[2];
    o[3] = (__bf16)v[3];
    ((bf16x4*)d)[i] = o;
  };
  int i = blockIdx.x * blockDim.x + threadIdx.x;
  const int stride = gridDim.x * blockDim.x;
  for (; i < TOT; i += stride) {
    int j = i;
    if (j < NX) {
      cast4(x, xb, j);
    } else if ((j -= NX) < NW1) {
      cast4(wq, wb, j);
    } else if ((j -= NW1) < NW2) {
      cast4(wk, wb + (size_t)NW1 * 4, j);
    } else if ((j -= NW2) < NW2) {
      cast4(wv, wb + (size_t)(NW1 + NW2) * 4, j);
    } else if ((j -= NW2) < NP) {
      cast4(wp, wpb, j);
    } else {
      j -= NP;  // rope table: entry (s, jj)
      const int s = j >> 5, jj = j & 31;
      const float inv = powf(10000.0f, -(float)jj * 0.03125f);
      const float ang = (float)s * inv;
      tab[j] = make_float2(cosf(ang), sinf(ang));
    }
  }
}

// ---------------- 2/4) B^T GEMM: 128^2, 3-buffer counted-vmcnt pipeline ------
// (R12 structure, measured equal-best: MfmaUtil ~29, conflicts 0.)
// FUSE epilogue: bn 0-19 (q,k heads) -> RMSNorm + partial RoPE + q log2
// prescale; bn 20-23 (v heads) -> plain qkv store PLUS in-LDS transpose
// (pad-140 layout, conflict-free) writing vt[b,kvh][d][kv^((d&7)<<3)].
template <typename CT, bool FUSE>
__global__ __launch_bounds__(256) void gemm_bt(const __bf16* __restrict__ A,
                                               const __bf16* __restrict__ B,
                                               CT* __restrict__ C, int N, int K, int nbn,
                                               const float2* __restrict__ tab,
                                               __bf16* __restrict__ vt) {
  __shared__ __align__(16) __bf16 SM[24576];  // 48 KB: 3xAs(4096) | 3xBs(4096)
  __bf16* Asb = SM;
  __bf16* Bsb = SM + 12288;
  const int nwg = gridDim.x;
  const int id = blockIdx.x;
  const int xid = (id & 7) * (nwg >> 3) + (id >> 3);
  const int bm = xid / nbn;
  const int bn = xid - bm * nbn;
  const int t = threadIdx.x;
  const int l = t & 63, w = t >> 6;
  const int wr = w >> 1, wc = w & 1;
  const int lr = l & 15, lk = l >> 4;
  const __bf16* Ab = A + (size_t)bm * 128 * K;
  const __bf16* Bb = B + (size_t)bn * 128 * K;
  const int srow = t >> 2;                              // 0..63 (also +64)
  const int scol = ((t & 3) ^ ((srow >> 1) & 3)) << 3;  // inverse swizzle on src
  f32x4 acc[4][4] = {};

  auto stage = [&](int kt, int buf) {
    const int k0 = kt << 5;
    gload_lds16(Ab + (size_t)srow * K + k0 + scol, &Asb[buf * 4096 + t * 8]);
    gload_lds16(Ab + (size_t)(srow + 64) * K + k0 + scol, &Asb[buf * 4096 + 2048 + t * 8]);
    gload_lds16(Bb + (size_t)srow * K + k0 + scol, &Bsb[buf * 4096 + t * 8]);
    gload_lds16(Bb + (size_t)(srow + 64) * K + k0 + scol, &Bsb[buf * 4096 + 2048 + t * 8]);
  };

  stage(0, 0);
  stage(1, 1);
  asm volatile("s_waitcnt vmcnt(4)" ::: "memory");
  __builtin_amdgcn_s_barrier();

  const int NT = K >> 5;
  int cur = 0;
  for (int kt = 0; kt < NT; ++kt) {
    if (kt + 2 < NT) {
      int c2 = cur + 2;
      if (c2 >= 3) c2 -= 3;
      stage(kt + 2, c2);  // issue 2-ahead (async)
    }

    bf16x8 af[4], bfr[4];
#pragma unroll
    for (int m = 0; m < 4; ++m) {
      const int row = wr * 64 + m * 16 + lr;
      af[m] = *(const bf16x8*)&Asb[cur * 4096 + row * 32 + ((lk ^ ((row >> 1) & 3)) << 3)];
    }
#pragma unroll
    for (int n = 0; n < 4; ++n) {
      const int row = wc * 64 + n * 16 + lr;
      bfr[n] = *(const bf16x8*)&Bsb[cur * 4096 + row * 32 + ((lk ^ ((row >> 1) & 3)) << 3)];
    }
#pragma unroll
    for (int m = 0; m < 4; ++m)
#pragma unroll
      for (int n = 0; n < 4; ++n) acc[m][n] = MFMA16x16x32(af[m], bfr[n], acc[m][n]);

    if (kt + 2 < NT)
      asm volatile("s_waitcnt vmcnt(4)" ::: "memory");
    else
      asm volatile("s_waitcnt vmcnt(0)" ::: "memory");
    __builtin_amdgcn_s_barrier();

    ++cur;
    if (cur == 3) cur = 0;
  }

  if constexpr (FUSE) {
    if (bn < 20) {
      // q/k heads: RMSNorm + partial RoPE (+ q log2-domain prescale)
      __syncthreads();  // drain all LDS traffic before SM reuse
      float* Ls = (float*)SM;  // [2][128] row sum-of-squares per col-wave
      float ssp[4][4];
#pragma unroll
      for (int m = 0; m < 4; ++m)
#pragma unroll
        for (int i = 0; i < 4; ++i) {
          float s = 0.0f;
#pragma unroll
          for (int n = 0; n < 4; ++n) s += acc[m][n][i] * acc[m][n][i];
#pragma unroll
          for (int off = 1; off < 16; off <<= 1) s += __shfl_xor(s, off);
          ssp[m][i] = s;
        }
      if (lr == 0) {
#pragma unroll
        for (int m = 0; m < 4; ++m)
#pragma unroll
          for (int i = 0; i < 4; ++i)
            Ls[wc * 128 + wr * 64 + m * 16 + lk * 4 + i] = ssp[m][i];
      }
      __syncthreads();
      const bool isq = (bn < 16);
      const float qs = isq ? 0.1275174457f : 1.0f;  // (1/sqrt(128))*log2(e)
#pragma unroll
      for (int m = 0; m < 4; ++m) {
#pragma unroll
        for (int i = 0; i < 4; ++i) {
          const int rl = wr * 64 + m * 16 + lk * 4 + i;
          const int rg = bm * 128 + rl;
          const float sc =
              rsqrtf((Ls[rl] + Ls[128 + rl]) * (1.0f / 128.0f) +
                     1.1920928955078125e-07f) *
              qs;
          CT* Cr = C + (size_t)rg * N + bn * 128;
          if (wc == 0) {
            const int s = rg & 1023;
#pragma unroll
            for (int n = 0; n < 2; ++n) {
              const int j = n * 16 + lr;
              const float2 cs = tab[s * 32 + j];
              const float x1 = acc[m][n][i], x2 = acc[m][n + 2][i];
              Cr[j] = (CT)((x1 * cs.x + x2 * cs.y) * sc);
              Cr[j + 32] = (CT)((-x1 * cs.y + x2 * cs.x) * sc);
            }
          } else {
#pragma unroll
            for (int n = 0; n < 4; ++n)
              Cr[64 + n * 16 + lr] = (CT)(acc[m][n][i] * sc);
          }
        }
      }
      return;
    } else {
      // v heads: plain qkv store + LDS transpose -> vt (pre-swizzled)
#pragma unroll
      for (int m = 0; m < 4; ++m) {
        const int row0 = bm * 128 + wr * 64 + m * 16 + lk * 4;
#pragma unroll
        for (int n = 0; n < 4; ++n) {
          const int col = bn * 128 + wc * 64 + n * 16 + lr;
#pragma unroll
          for (int i = 0; i < 4; ++i)
            C[(size_t)(row0 + i) * N + col] = (CT)acc[m][n][i];
        }
      }
      __syncthreads();  // drain all LDS traffic before SM reuse
      __bf16* T = SM;   // [128][140] pad-140 transpose buffer (35840 B)
#pragma unroll
      for (int m = 0; m < 4; ++m) {
#pragma unroll
        for (int n = 0; n < 4; ++n) {
          const int cl = wc * 64 + n * 16 + lr;
#pragma unroll
          for (int i = 0; i < 4; ++i) {
            const int rl = wr * 64 + m * 16 + lk * 4 + i;
            T[rl * 140 + cl] = (__bf16)acc[m][n][i];
          }
        }
      }
      __syncthreads();
      const int bb = bm >> 3, s0g = (bm & 7) << 7;
      __bf16* dst = vt + (size_t)(bb * 4 + (bn - 20)) * 131072;
#pragma unroll
      for (int r = 0; r < 8; ++r) {
        const int off = r * 2048 + t * 8;
        const int dd = off >> 7, sc = off & 127;
        bf16x8 v;
#pragma unroll
        for (int j = 0; j < 8; ++j) v[j] = T[(sc + j) * 140 + dd];
        *(bf16x8*)&dst[(size_t)dd * 1024 + ((s0g + sc) ^ ((dd & 7) << 3))] = v;
      }
      return;
    }
  }

#pragma unroll
  for (int m = 0; m < 4; ++m) {
    const int row0 = bm * 128 + wr * 64 + m * 16 + lk * 4;
#pragma unroll
    for (int n = 0; n < 4; ++n) {
      const int col = bn * 128 + wc * 64 + n * 16 + lr;
#pragma unroll
      for (int i = 0; i < 4; ++i) C[(size_t)(row0 + i) * N + col] = (CT)acc[m][n][i];
    }
  }
}

// ---------------- 3) causal flash attention + v-projection correction ------
// KVBLK=128 SEQUENTIAL-PAIR + ones-MFMA row-sum denom + defer-max:
// 256 blocks (=1/CU) x 512 threads (8 waves); passes (7-pr, pr) => exactly
// 9 kv-iterations/block. Softmax denominator via MFMA(P, ones) row-sum.
// O/l rescale skipped unless running max grew by >8 (log2 domain).
__global__ __launch_bounds__(512) void attn_fwd(const __bf16* __restrict__ qkv,
                                                const __bf16* __restrict__ vt,
                                                __bf16* __restrict__ y) {
  const int id = blockIdx.x;
  const int g = (id & 7) | (((id >> 3) & 1) << 3);  // (b,kvh) group 0..15
  const int b = g >> 2, kvh = g & 3;
  const int hi = (id >> 4) & 3;
  const int pr = (id >> 6) & 3;
  const int h = kvh * 4 + hi;

  const int t = threadIdx.x;
  const int l = t & 63, w = t >> 6;  // 8 waves
  const int lr = l & 15, lk = l >> 4;
  const int lr8 = lr & 7;

  __shared__ __bf16 Ks[2][128 * 128];
  __shared__ __bf16 Vs[2][128 * 128];
  __shared__ __bf16 Ps[8][16 * 128];

  const size_t rb = (size_t)b * 1024;
  const __bf16* Kg0 = qkv + rb * 3072 + 2048 + kvh * 128;
  const __bf16* Vtb = vt + (size_t)(b * 4 + kvh) * 128 * 1024;

  const int srow = t >> 4;  // 0..31
  const int scg = t & 15;
  const int kcolg = (scg ^ (srow & 7)) << 3;  // inverse swizzle on K source

  auto stageK = [&](int kv0, int buf) {
#pragma unroll
    for (int r = 0; r < 4; ++r)
      gload_lds16(Kg0 + (size_t)(kv0 + r * 32 + srow) * 3072 + kcolg,
                  &Ks[buf][0] + r * 4096 + t * 8);
  };
  auto stageV = [&](int kv0, int buf) {
#pragma unroll
    for (int r = 0; r < 4; ++r)
      gload_lds16(Vtb + (size_t)(r * 32 + srow) * 1024 + kv0 + scg * 8,
                  &Vs[buf][0] + r * 4096 + t * 8);
  };

  bf16x8 onesb;
#pragma unroll
  for (int j = 0; j < 8; ++j) onesb[j] = (__bf16)1.0f;

#pragma unroll 1
  for (int pass = 0; pass < 2; ++pass) {
    const int qt = pass ? pr : (7 - pr);  // heavy pass first
    const int q0 = qt << 7;
    const int nt = qt + 1;

    bf16x8 aq[4];
    {
      const __bf16* qrow = qkv + (rb + q0 + w * 16 + lr) * 3072 + h * 128 + lk * 8;
#pragma unroll
      for (int kk = 0; kk < 4; ++kk) aq[kk] = *(const bf16x8*)(qrow + kk * 32);
    }

    float m_i[4], l_i[4];
    f32x4 o[8] = {};
#pragma unroll
    for (int i = 0; i < 4; ++i) {
      m_i[i] = -1e30f;
      l_i[i] = 0.0f;
    }

    const int rowg0 = q0 + w * 16 + lk * 4;

    stageK(0, 0);
    stageV(0, 0);
    __syncthreads();  // drains vmcnt -> buf0 ready

    for (int tt = 0; tt < nt; ++tt) {
      const int kv0 = tt << 7;
      const int cur = tt & 1;
      if (tt + 1 < nt) {
        stageK(kv0 + 128, cur ^ 1);
        stageV(kv0 + 128, cur ^ 1);
      }

      // S = Q K^T (log2-domain: q pre-scaled in gemm epilogue)
      f32x4 sacc[8] = {};
      __builtin_amdgcn_s_setprio(1);
#pragma unroll
      for (int kk = 0; kk < 4; ++kk) {
#pragma unroll
        for (int n = 0; n < 8; ++n) {
          const bf16x8 bk = *(const bf16x8*)&Ks[cur][(n * 16 + lr) * 128 +
                                                    ((kk * 32 + lk * 8) ^ (lr8 << 3))];
          sacc[n] = MFMA16x16x32(aq[kk], bk, sacc[n]);
        }
      }
      __builtin_amdgcn_s_setprio(0);

      // causal mask (diagonal tile only) + tile row-max
      float pm[4];
#pragma unroll
      for (int i = 0; i < 4; ++i) pm[i] = -1e30f;
      if (tt == qt) {
#pragma unroll
        for (int n = 0; n < 8; ++n) {
          const int colg = kv0 + n * 16 + lr;
#pragma unroll
          for (int i = 0; i < 4; ++i) {
            if (colg > rowg0 + i) sacc[n][i] = -1e30f;
            pm[i] = fmaxf(pm[i], sacc[n][i]);
          }
        }
      } else {
#pragma unroll
        for (int n = 0; n < 8; ++n)
#pragma unroll
          for (int i = 0; i < 4; ++i) pm[i] = fmaxf(pm[i], sacc[n][i]);
      }
#pragma unroll
      for (int i = 0; i < 4; ++i) {
        pm[i] = fmaxf(pm[i], __shfl_xor(pm[i], 1));
        pm[i] = fmaxf(pm[i], __shfl_xor(pm[i], 2));
        pm[i] = fmaxf(pm[i], __shfl_xor(pm[i], 4));
        pm[i] = fmaxf(pm[i], __shfl_xor(pm[i], 8));
      }

      // defer-max: rescale only when the running max grew by >8 (log2)
      const float dm = fmaxf(fmaxf(pm[0] - m_i[0], pm[1] - m_i[1]),
                             fmaxf(pm[2] - m_i[2], pm[3] - m_i[3]));
      if (__any(dm > 8.0f)) {
#pragma unroll
        for (int i = 0; i < 4; ++i) {
          const float mn = fmaxf(m_i[i], pm[i]);
          const float al = EXP2(m_i[i] - mn);
          m_i[i] = mn;
          l_i[i] *= al;
#pragma unroll
          for (int f = 0; f < 8; ++f) o[f][i] *= al;
        }
      }

      // P = exp2(S - m) -> Ps (bf16, swizzled)
#pragma unroll
      for (int n = 0; n < 8; ++n) {
#pragma unroll
        for (int i = 0; i < 4; ++i) {
          const float p = EXP2(sacc[n][i] - m_i[i]);
          const int prow = lk * 4 + i;
          Ps[w][prow * 128 + ((n * 16 + lr) ^ ((prow & 7) << 3))] = (__bf16)p;
        }
      }

      // O += P V ; l += P·1 (ones-MFMA row-sum, no shuffles)
      f32x4 lsum = {};
      __builtin_amdgcn_s_setprio(1);
#pragma unroll
      for (int ks = 0; ks < 4; ++ks) {
        const bf16x8 pa =
            *(const bf16x8*)&Ps[w][lr * 128 + ((ks * 32 + lk * 8) ^ (lr8 << 3))];
        lsum = MFMA16x16x32(pa, onesb, lsum);
#pragma unroll
        for (int f = 0; f < 8; ++f) {
          const bf16x8 vb = *(const bf16x8*)&Vs[cur][(f * 16 + lr) * 128 +
                                                     ((ks * 32 + lk * 8) ^ (lr8 << 3))];
          o[f] = MFMA16x16x32(pa, vb, o[f]);
        }
      }
      __builtin_amdgcn_s_setprio(0);
#pragma unroll
      for (int i = 0; i < 4; ++i) l_i[i] += lsum[i];

      __syncthreads();  // next tile staged (vmcnt drained) + all LDS reads done
    }

    // epilogue: normalize, v-projection correction, store bf16
#pragma unroll
    for (int i = 0; i < 4; ++i) {
      const int sg = rowg0 + i;
      const size_t mg = rb + sg;
      const __bf16* vp = qkv + mg * 3072 + 2560 + kvh * 128;
      const float invl = 1.0f / l_i[i];
      float vvv[8], yvv[8];
      float dyv = 0.0f, dvv = 0.0f;
#pragma unroll
      for (int f = 0; f < 8; ++f) {
        const float vf = (float)vp[f * 16 + lr];
        const float yf = o[f][i] * invl;
        vvv[f] = vf;
        yvv[f] = yf;
        dyv += yf * vf;
        dvv += vf * vf;
      }
#pragma unroll
      for (int off = 1; off < 16; off <<= 1) {
        dyv += __shfl_xor(dyv, off);
        dvv += __shfl_xor(dvv, off);
      }
      const float proj = dyv / fmaxf(dvv, 1e-6f);
      __bf16* yp = y + mg * 2048 + h * 128;
#pragma unroll
      for (int f = 0; f < 8; ++f) yp[f * 16 + lr] = (__bf16)(yvv[f] - proj * vvv[f]);
    }
  }
}

// ---------------------------------------------------------------------------
extern "C" void kernel_launch(void* const* d_in, const int* in_sizes, int n_in,
                              void* d_out, int out_size, void* d_ws, size_t ws_size,
                              hipStream_t stream) {
  const float* x = (const float*)d_in[0];
  const float* Wq = (const float*)d_in[2];
  const float* Wk = (const float*)d_in[3];
  const float* Wv = (const float*)d_in[4];
  const float* Wp = (const float*)d_in[5];
  float* out = (float*)d_out;

  __bf16* xb = (__bf16*)d_ws;                // 4096x2048
  __bf16* Wb = xb + (size_t)4096 * 2048;     // 3072x2048  [Wq;Wk;Wv]
  __bf16* Wpb = Wb + (size_t)3072 * 2048;    // 2048x2048
  __bf16* qkv = Wpb + (size_t)2048 * 2048;   // 4096x3072
  __bf16* yb = qkv + (size_t)4096 * 3072;    // 4096x2048
  float2* tab = (float2*)(yb + (size_t)4096 * 2048);  // 1024x32 cos/sin
  __bf16* vt = (__bf16*)(tab + 32768);       // 16x128x1024 transposed V

  prep<<<2048, 256, 0, stream>>>(x, Wq, Wk, Wv, Wp, xb, Wb, Wpb, tab);

  gemm_bt<__bf16, true><<<768, 256, 0, stream>>>(xb, Wb, qkv, 3072, 2048, 24, tab, vt);
  attn_fwd<<<256, 512, 0, stream>>>(qkv, vt, yb);
  gemm_bt<float, false><<<512, 256, 0, stream>>>(yb, Wpb, out, 2048, 2048, 16, nullptr,
                                                 nullptr);
}